// Round 4
// baseline (1249.966 us; speedup 1.0000x reference)
//
#include <hip/hip_runtime.h>
#include <cstdint>
#include <cstddef>

typedef unsigned short u16;
typedef __bf16 bf16x8 __attribute__((ext_vector_type(8)));
typedef float    f32x4 __attribute__((ext_vector_type(4)));
typedef unsigned short u16x8 __attribute__((ext_vector_type(8)));
typedef unsigned short u16x4 __attribute__((ext_vector_type(4)));

#define MFMA16(a,b,c) __builtin_amdgcn_mfma_f32_16x16x32_bf16(a,b,c,0,0,0)

__device__ __forceinline__ float bf2f(u16 u){ return __uint_as_float(((unsigned)u)<<16); }
__device__ __forceinline__ u16 f2bf(float f){
  unsigned x = __float_as_uint(f);
  unsigned r = x + 0x7fffu + ((x>>16)&1u);
  return (u16)(r>>16);
}
__device__ __forceinline__ float wred(float v){
  #pragma unroll
  for (int o=32;o;o>>=1) v += __shfl_xor(v,o,64);
  return v;
}
__device__ __forceinline__ float siluf(float x){ return x/(1.f+__expf(-x)); }

// ---------------- zero a float buffer ----------------
__global__ __launch_bounds__(256) void k_zero(float* __restrict__ p, int n){
  int i = blockIdx.x*256 + threadIdx.x;
  if (i < n) p[i] = 0.f;
}

// ---------------- fp32 -> bf16 convert ----------------
__global__ __launch_bounds__(256) void k_cvt(const float* __restrict__ src,
                                             u16* __restrict__ dst, int n){
  int i = (blockIdx.x*256 + threadIdx.x)*4;
  if (i < n){
    float4 f = *(const float4*)(src + i);
    u16x4 o; o[0]=f2bf(f.x); o[1]=f2bf(f.y); o[2]=f2bf(f.z); o[3]=f2bf(f.w);
    *(u16x4*)(dst + i) = o;
  }
}

// ---------------- transpose + cvt + pad: dst[n][k] = (n<C && k<R) ? src[k][n] : 0
__global__ __launch_bounds__(256) void k_tr(const float* __restrict__ src, u16* __restrict__ dst,
                                            int R, int C, int Rp, int Cp){
  __shared__ float t[32][33];
  int n0 = blockIdx.x*32, k0 = blockIdx.y*32;
  int tx = threadIdx.x & 31, ty = threadIdx.x >> 5;
  #pragma unroll
  for (int j=0;j<4;j++){
    int k = k0 + ty + j*8, nn = n0 + tx;
    t[ty + j*8][tx] = (k < R && nn < C) ? src[k*C + nn] : 0.f;
  }
  __syncthreads();
  #pragma unroll
  for (int j=0;j<4;j++){
    int nn = n0 + ty + j*8, k = k0 + tx;
    dst[nn*Rp + k] = f2bf(t[tx][ty + j*8]);
  }
}

// w2t[j][k] = rw2[k][j], j<16, k<2160 (pad to 2176)
__global__ __launch_bounds__(256) void k_pad_w2t(const float* __restrict__ src, u16* __restrict__ dst){
  int k = blockIdx.x*256 + threadIdx.x;
  int j = blockIdx.y;
  if (k < 2176) dst[j*2176 + k] = (k < 2160) ? f2bf(src[k*16 + j]) : (u16)0;
}
__global__ __launch_bounds__(256) void k_pad_b1(const float* __restrict__ src, float* __restrict__ dst){
  int i = blockIdx.x*256 + threadIdx.x;
  if (i < 2176) dst[i] = (i<2160) ? src[i] : 0.f;
}

// ---------------- per-(bh,chunk) k transpose: kTb[chk][d][tl] = kn[(b,t),(h,d)] ----------------
__global__ __launch_bounds__(256) void k_trk(const u16* __restrict__ kn, u16* __restrict__ kTb){
  __shared__ u16 vs[32][264];
  const int g = blockIdx.x;          // bh*128 + nc
  const int bh = g >> 7, nc = g & 127;
  const int b = bh >> 2, h = bh & 3;
  const int tid = threadIdx.x;
  const int rr = tid >> 3, cb = (tid & 7) * 32;
  const u16* src = kn + (size_t)(b*4096 + nc*32 + rr)*1024 + h*256 + cb;
  #pragma unroll
  for (int v=0; v<4; ++v){
    u16x8 x = *(const u16x8*)(src + v*8);
    *(u16x8*)&vs[rr][cb + v*8] = x;
  }
  __syncthreads();
  u16* dst = kTb + ((size_t)g*256 + tid)*32;
  #pragma unroll
  for (int v=0; v<4; ++v){
    u16x8 o;
    #pragma unroll
    for (int e=0; e<8; e++) o[e] = vs[v*8 + e][tid];
    *(u16x8*)(dst + v*8) = o;
  }
}

// ---------------- bf16 GEMM: C[M,N] = A[M,K] @ Bt[N,K]^T ----------------
__global__ __launch_bounds__(256,2) void k_gemm(
    const u16* __restrict__ A, const u16* __restrict__ Bt, void* __restrict__ Cvp,
    int M, int N, int K, int out_f32)
{
  __shared__ u16 As[2][128*64];
  __shared__ u16 Bs[2][128*64];
  const int tid = threadIdx.x;
  const int lane = tid & 63, wv = tid >> 6;
  const int wm = (wv>>1)*64, wn = (wv&1)*64;
  const int r15 = lane & 15, q4 = lane >> 4;
  const int bm0 = blockIdx.y*128, bn0 = blockIdx.x*128;
  const int srow = tid>>3, sch = tid&7;
  const int nk = K >> 6;

  const f32x4 fz = {0.f,0.f,0.f,0.f};
  f32x4 acc[4][4];
  #pragma unroll
  for (int i=0;i<4;i++){
    #pragma unroll
    for (int j=0;j<4;j++) acc[i][j] = fz;
  }

  { // preload tile 0 into buf 0
    u16x8 ca[4], cb[4];
    #pragma unroll
    for (int i=0;i<4;i++){
      int r = i*32 + srow;
      ca[i] = *(const u16x8*)(A  + (size_t)(bm0+r)*K + sch*8);
      cb[i] = *(const u16x8*)(Bt + (size_t)(bn0+r)*K + sch*8);
    }
    #pragma unroll
    for (int i=0;i<4;i++){
      int r = i*32 + srow;
      int byt = r*128 + ((sch ^ (r&7))*16);
      *(u16x8*)((char*)(&As[0][0]) + byt) = ca[i];
      *(u16x8*)((char*)(&Bs[0][0]) + byt) = cb[i];
    }
  }
  int cur = 0;
  for (int t=0; t<nk; ++t){
    u16x8 na[4], nb[4];
    if (t+1 < nk){
      const int kt = (t+1)<<6;
      #pragma unroll
      for (int i=0;i<4;i++){
        int r = i*32 + srow;
        na[i] = *(const u16x8*)(A  + (size_t)(bm0+r)*K + kt + sch*8);
        nb[i] = *(const u16x8*)(Bt + (size_t)(bn0+r)*K + kt + sch*8);
      }
    }
    __syncthreads();
    const u16* as_ = &As[cur][0];
    const u16* bs_ = &Bs[cur][0];
    #pragma unroll
    for (int kk=0; kk<2; ++kk){
      bf16x8 av[4], bv[4];
      #pragma unroll
      for (int mi=0;mi<4;mi++){
        int row = wm + mi*16 + r15;
        int ch  = kk*4 + q4;
        av[mi] = *(const bf16x8*)((const char*)as_ + row*128 + ((ch ^ (row&7))*16));
      }
      #pragma unroll
      for (int ni=0;ni<4;ni++){
        int row = wn + ni*16 + r15;
        int ch  = kk*4 + q4;
        bv[ni] = *(const bf16x8*)((const char*)bs_ + row*128 + ((ch ^ (row&7))*16));
      }
      #pragma unroll
      for (int mi=0;mi<4;mi++){
        #pragma unroll
        for (int ni=0;ni<4;ni++)
          acc[mi][ni] = MFMA16(av[mi], bv[ni], acc[mi][ni]);
      }
    }
    if (t+1 < nk){
      #pragma unroll
      for (int i=0;i<4;i++){
        int r = i*32 + srow;
        int byt = r*128 + ((sch ^ (r&7))*16);
        *(u16x8*)((char*)(&As[cur^1][0]) + byt) = na[i];
        *(u16x8*)((char*)(&Bs[cur^1][0]) + byt) = nb[i];
      }
    }
    cur ^= 1;
  }
  float* Cf = (float*)Cvp;
  u16*  Cb2 = (u16*)Cvp;
  #pragma unroll
  for (int mi=0;mi<4;mi++){
    #pragma unroll
    for (int ni=0;ni<4;ni++){
      int gr = bm0 + wm + mi*16 + q4*4;
      int gc = bn0 + wn + ni*16 + r15;
      #pragma unroll
      for (int rg=0; rg<4; ++rg){
        float v = acc[mi][ni][rg];
        size_t off = (size_t)(gr+rg)*N + gc;
        if (out_f32) Cf[off] = v; else Cb2[off] = f2bf(v);
      }
    }
  }
}

// ---------------- fused router GEMM: logits += silu(feat@w1+b1) @ w2 ----------------
union SMu {
  struct { u16 As[2][128*64]; u16 Bs[2][128*64]; } g;
  u16 h1s[128][136];
};
__global__ __launch_bounds__(256,2) void k_gemm_router(
    const u16* __restrict__ A, const u16* __restrict__ Bt,
    const float* __restrict__ bias, const u16* __restrict__ w2t,
    float* __restrict__ logits)
{
  __shared__ SMu sm;
  const int tid = threadIdx.x;
  const int lane = tid & 63, wv = tid >> 6;
  const int wm = (wv>>1)*64, wn = (wv&1)*64;
  const int r15 = lane & 15, q4 = lane >> 4;
  const int bm0 = blockIdx.y*128, bn0 = blockIdx.x*128;
  const int srow = tid>>3, sch = tid&7;
  const int K = 1088, nk = 17;

  const f32x4 fz = {0.f,0.f,0.f,0.f};
  f32x4 acc[4][4];
  #pragma unroll
  for (int i=0;i<4;i++){
    #pragma unroll
    for (int j=0;j<4;j++) acc[i][j] = fz;
  }
  {
    u16x8 ca[4], cb[4];
    #pragma unroll
    for (int i=0;i<4;i++){
      int r = i*32 + srow;
      ca[i] = *(const u16x8*)(A  + (size_t)(bm0+r)*K + sch*8);
      cb[i] = *(const u16x8*)(Bt + (size_t)(bn0+r)*K + sch*8);
    }
    #pragma unroll
    for (int i=0;i<4;i++){
      int r = i*32 + srow;
      int byt = r*128 + ((sch ^ (r&7))*16);
      *(u16x8*)((char*)(&sm.g.As[0][0]) + byt) = ca[i];
      *(u16x8*)((char*)(&sm.g.Bs[0][0]) + byt) = cb[i];
    }
  }
  int cur = 0;
  for (int t=0; t<nk; ++t){
    u16x8 na[4], nb[4];
    if (t+1 < nk){
      const int kt = (t+1)<<6;
      #pragma unroll
      for (int i=0;i<4;i++){
        int r = i*32 + srow;
        na[i] = *(const u16x8*)(A  + (size_t)(bm0+r)*K + kt + sch*8);
        nb[i] = *(const u16x8*)(Bt + (size_t)(bn0+r)*K + kt + sch*8);
      }
    }
    __syncthreads();
    const u16* as_ = &sm.g.As[cur][0];
    const u16* bs_ = &sm.g.Bs[cur][0];
    #pragma unroll
    for (int kk=0; kk<2; ++kk){
      bf16x8 av[4], bv[4];
      #pragma unroll
      for (int mi=0;mi<4;mi++){
        int row = wm + mi*16 + r15;
        int ch  = kk*4 + q4;
        av[mi] = *(const bf16x8*)((const char*)as_ + row*128 + ((ch ^ (row&7))*16));
      }
      #pragma unroll
      for (int ni=0;ni<4;ni++){
        int row = wn + ni*16 + r15;
        int ch  = kk*4 + q4;
        bv[ni] = *(const bf16x8*)((const char*)bs_ + row*128 + ((ch ^ (row&7))*16));
      }
      #pragma unroll
      for (int mi=0;mi<4;mi++){
        #pragma unroll
        for (int ni=0;ni<4;ni++)
          acc[mi][ni] = MFMA16(av[mi], bv[ni], acc[mi][ni]);
      }
    }
    if (t+1 < nk){
      #pragma unroll
      for (int i=0;i<4;i++){
        int r = i*32 + srow;
        int byt = r*128 + ((sch ^ (r&7))*16);
        *(u16x8*)((char*)(&sm.g.As[cur^1][0]) + byt) = na[i];
        *(u16x8*)((char*)(&sm.g.Bs[cur^1][0]) + byt) = nb[i];
      }
    }
    cur ^= 1;
  }
  __syncthreads();   // done with As/Bs; reuse as h1s
  #pragma unroll
  for (int mi=0;mi<4;mi++){
    #pragma unroll
    for (int ni=0;ni<4;ni++){
      int lr = wm + mi*16 + q4*4;
      int lc = wn + ni*16 + r15;
      float bv_ = bias[bn0 + lc];
      #pragma unroll
      for (int rg=0; rg<4; ++rg)
        sm.h1s[lr+rg][lc] = f2bf(siluf(acc[mi][ni][rg] + bv_));
    }
  }
  __syncthreads();
  f32x4 lacc[2] = {fz, fz};
  #pragma unroll
  for (int rt=0; rt<2; ++rt){
    #pragma unroll
    for (int ks=0; ks<4; ++ks){
      bf16x8 a = *(const bf16x8*)((const char*)&sm.h1s[wv*32 + rt*16 + r15][0] + ks*64 + q4*16);
      bf16x8 b = *(const bf16x8*)(w2t + r15*2176 + bn0 + ks*32 + q4*8);
      lacc[rt] = MFMA16(a, b, lacc[rt]);
    }
  }
  #pragma unroll
  for (int rt=0; rt<2; ++rt){
    #pragma unroll
    for (int rg=0; rg<4; ++rg){
      int m = bm0 + wv*32 + rt*16 + q4*4 + rg;
      atomicAdd(&logits[m*16 + r15], lacc[rt][rg]);
    }
  }
}

// ---------------- softmax + floor over logits (in place) ----------------
__global__ __launch_bounds__(256) void k_softm(float* __restrict__ p, const float* __restrict__ b2){
  int m = blockIdx.x*256 + threadIdx.x;
  float l[16];
  #pragma unroll
  for (int j=0;j<16;j++) l[j] = p[m*16+j] + b2[j];
  #pragma unroll
  for (int hh=0;hh<4;hh++){
    float l0=l[hh*4+0], l1=l[hh*4+1], l2=l[hh*4+2], l3=l[hh*4+3];
    float mx = fmaxf(fmaxf(l0,l1),fmaxf(l2,l3));
    float e0=__expf(l0-mx), e1=__expf(l1-mx), e2=__expf(l2-mx), e3=__expf(l3-mx);
    float iv = 1.f/(e0+e1+e2+e3);
    p[m*16+hh*4+0]=e0*iv*0.96f+0.01f;
    p[m*16+hh*4+1]=e1*iv*0.96f+0.01f;
    p[m*16+hh*4+2]=e2*iv*0.96f+0.01f;
    p[m*16+hh*4+3]=e3*iv*0.96f+0.01f;
  }
}

// ---------------- beta = sigmoid(X @ Wb) ----------------
__global__ __launch_bounds__(256) void k_beta(const u16* __restrict__ Xb,
                                              const float* __restrict__ Wb,
                                              float* __restrict__ beta){
  int m = blockIdx.x*4 + (threadIdx.x>>6);
  int lane = threadIdx.x & 63;
  float a0=0.f,a1=0.f,a2=0.f,a3=0.f;
  #pragma unroll 4
  for (int i=0;i<16;i++){
    int k = lane + i*64;
    float x = bf2f(Xb[m*1024 + k]);
    float4 wr = *(const float4*)(Wb + k*4);
    a0 += x*wr.x; a1 += x*wr.y; a2 += x*wr.z; a3 += x*wr.w;
  }
  a0 = wred(a0); a1 = wred(a1); a2 = wred(a2); a3 = wred(a3);
  if (lane == 0){
    beta[m*4+0] = 1.f/(1.f+__expf(-a0));
    beta[m*4+1] = 1.f/(1.f+__expf(-a1));
    beta[m*4+2] = 1.f/(1.f+__expf(-a2));
    beta[m*4+3] = 1.f/(1.f+__expf(-a3));
  }
}

// ---------------- causal K=4 depthwise conv + silu (+ per-head l2norm) ----------------
__global__ __launch_bounds__(256) void k_conv(const u16* __restrict__ raw,
                                              const float* __restrict__ cw,
                                              u16* __restrict__ outp, int do_norm){
  const int m = blockIdx.x;
  const int tid = threadIdx.x, lane = tid&63, hh = tid>>6;
  const int l = m & 4095;
  const int cbase = hh*256 + lane*4;
  float x[4][4];
  #pragma unroll
  for (int j=0;j<4;j++){
    if (l >= j){
      u16x4 xv = *(const u16x4*)(raw + (m-j)*1024 + cbase);
      #pragma unroll
      for (int e=0;e<4;e++) x[j][e] = bf2f(xv[e]);
    } else {
      #pragma unroll
      for (int e=0;e<4;e++) x[j][e] = 0.f;
    }
  }
  float y[4]; float ss = 0.f;
  #pragma unroll
  for (int e=0;e<4;e++){
    int c = cbase + e;
    float yy = x[0][e]*cw[c*4+3] + x[1][e]*cw[c*4+2] + x[2][e]*cw[c*4+1] + x[3][e]*cw[c*4+0];
    yy = siluf(yy);
    y[e] = yy; ss += yy*yy;
  }
  if (do_norm){
    ss = wred(ss);
    float sc = rsqrtf(ss + 1e-12f);
    #pragma unroll
    for (int e=0;e<4;e++) y[e] *= sc;
  }
  u16x4 o;
  #pragma unroll
  for (int e=0;e<4;e++) o[e] = f2bf(y[e]);
  *(u16x4*)(outp + m*1024 + cbase) = o;
}

// ---------------- local (K=7) + mid (K=25) depthwise causal convs on v ----------------
__global__ __launch_bounds__(256) void k_localmid(const u16* __restrict__ v,
                                                  const float* __restrict__ lw,
                                                  const float* __restrict__ mw,
                                                  u16* __restrict__ lo, u16* __restrict__ mo){
  __shared__ u16 vs[56][256];
  const int lt0 = blockIdx.x*32;
  const int b = blockIdx.y;
  const int c0 = blockIdx.z*256;
  const int tid = threadIdx.x;
  #pragma unroll
  for (int i=0;i<7;i++){
    int flat = tid + i*256;
    int row = flat >> 5;
    int cc = (flat & 31)*8;
    int tok = lt0 - 24 + row;
    u16x8 val = {0,0,0,0,0,0,0,0};
    if (tok >= 0) val = *(const u16x8*)(v + (b*4096 + tok)*1024 + c0 + cc);
    *(u16x8*)&vs[row][cc] = val;
  }
  __syncthreads();
  const int c = tid;
  float lwr[7], mwr[25];
  #pragma unroll
  for (int i=0;i<7;i++) lwr[i] = lw[(c0+c)*7 + i];
  #pragma unroll
  for (int i=0;i<25;i++) mwr[i] = mw[(c0+c)*25 + i];
  for (int lt=0; lt<32; ++lt){
    float a7=0.f, a25=0.f;
    #pragma unroll
    for (int t=0;t<25;t++) a25 += bf2f(vs[lt+t][c]) * mwr[t];
    #pragma unroll
    for (int t=0;t<7;t++)  a7  += bf2f(vs[18+lt+t][c]) * lwr[t];
    int m = b*4096 + lt0 + lt;
    lo[m*1024 + c0 + c] = f2bf(a7);
    mo[m*1024 + c0 + c] = f2bf(a25);
  }
}

// ---------------- chunk-local: T=(I-A)^-1 ; u=T(vB) ; w=T(kB) ; attn=tril(q k^T) ----------------
__global__ __launch_bounds__(256,2) void k_chunk(
    const u16* __restrict__ qn, const u16* __restrict__ kn, const u16* __restrict__ v,
    const float* __restrict__ beta, u16* __restrict__ u_, u16* __restrict__ w_,
    u16* __restrict__ attnb)
{
  const int chk = blockIdx.x;
  const int nc = chk & 127;
  const int bh = chk >> 7;
  const int b = bh >> 2, h = bh & 3;
  const int tok0 = b*4096 + nc*32;
  const int tid = threadIdx.x, lane = tid&63, wv = tid>>6;
  const int r15 = lane&15, q4 = lane>>4;

  __shared__ u16 kbT[256][40];
  __shared__ u16 vbT[256][40];
  __shared__ float Tm[4][32][33];
  __shared__ u16 Xs[32][40];

  {
    int rr = tid >> 3;
    int cb = (tid & 7)*32;
    float bt = beta[(tok0 + rr)*4 + h];
    const u16* ksrc = kn + (tok0+rr)*1024 + h*256 + cb;
    const u16* vsrc = v  + (tok0+rr)*1024 + h*256 + cb;
    #pragma unroll
    for (int vvv=0; vvv<4; ++vvv){
      u16x8 kx = *(const u16x8*)(ksrc + vvv*8);
      u16x8 vx = *(const u16x8*)(vsrc + vvv*8);
      #pragma unroll
      for (int e=0;e<8;e++){
        kbT[cb + vvv*8 + e][rr] = f2bf(bf2f(kx[e]) * bt);
        vbT[cb + vvv*8 + e][rr] = f2bf(bf2f(vx[e]) * bt);
      }
    }
  }
  {
    const int i0 = (wv>>1)*16, j0 = (wv&1)*16;
    float bi = beta[(tok0 + i0 + r15)*4 + h];
    f32x4 tacc = {0.f,0.f,0.f,0.f};
    #pragma unroll
    for (int ks=0; ks<8; ++ks){
      u16x8 ar = *(const u16x8*)(kn + (tok0 + i0 + r15)*1024 + h*256 + ks*32 + q4*8);
      union { u16x8 u; bf16x8 bf; } au;
      #pragma unroll
      for (int e=0;e<8;e++) au.u[e] = f2bf(bf2f(ar[e]) * bi);
      bf16x8 bv = *(const bf16x8*)(kn + (tok0 + j0 + r15)*1024 + h*256 + ks*32 + q4*8);
      tacc = MFMA16(au.bf, bv, tacc);
    }
    #pragma unroll
    for (int rg=0; rg<4; ++rg){
      int i = i0 + q4*4 + rg, j = j0 + r15;
      float val = (i > j) ? -tacc[rg] : 0.f;
      Tm[0][i][j] = val;
      Tm[2][i][j] = val + ((i==j)?1.f:0.f);
    }
  }
  __syncthreads();
  // (I-A)^-1 = (I+A)(I+A^2)(I+A^4)(I+A^8)(I+A^16)  (A^32 = 0)
  int cbuf = 0, cx = 2;
  const int ii = tid >> 3, jj = (tid&7)*4;
  for (int s=0; s<4; ++s){
    int nb = cbuf^1, nx = cx^1;
    {
      float o0=0.f,o1=0.f,o2=0.f,o3=0.f;
      for (int k=0;k<32;k++){
        float a = Tm[cbuf][ii][k];
        o0 += a*Tm[cbuf][k][jj+0]; o1 += a*Tm[cbuf][k][jj+1];
        o2 += a*Tm[cbuf][k][jj+2]; o3 += a*Tm[cbuf][k][jj+3];
      }
      Tm[nb][ii][jj+0]=o0; Tm[nb][ii][jj+1]=o1; Tm[nb][ii][jj+2]=o2; Tm[nb][ii][jj+3]=o3;
    }
    __syncthreads();
    {
      float o0=Tm[cx][ii][jj+0], o1=Tm[cx][ii][jj+1], o2=Tm[cx][ii][jj+2], o3=Tm[cx][ii][jj+3];
      for (int k=0;k<32;k++){
        float a = Tm[nb][ii][k];
        o0 += a*Tm[cx][k][jj+0]; o1 += a*Tm[cx][k][jj+1];
        o2 += a*Tm[cx][k][jj+2]; o3 += a*Tm[cx][k][jj+3];
      }
      Tm[nx][ii][jj+0]=o0; Tm[nx][ii][jj+1]=o1; Tm[nx][ii][jj+2]=o2; Tm[nx][ii][jj+3]=o3;
    }
    __syncthreads();
    cbuf = nb; cx = nx;
  }
  {
    #pragma unroll
    for (int e=0;e<4;e++) Xs[ii][jj+e] = f2bf(Tm[cx][ii][jj+e]);
  }
  __syncthreads();
  // u = X @ vb ; w = X @ kb
  {
    #pragma unroll
    for (int nt=0; nt<4; ++nt){
      int n0 = wv*64 + nt*16;
      #pragma unroll
      for (int mt=0; mt<2; ++mt){
        bf16x8 a = *(const bf16x8*)((const char*)&Xs[mt*16 + r15][0] + q4*16);
        bf16x8 bu = *(const bf16x8*)((const char*)&vbT[n0 + r15][0] + q4*16);
        bf16x8 bw = *(const bf16x8*)((const char*)&kbT[n0 + r15][0] + q4*16);
        f32x4 ua = {0.f,0.f,0.f,0.f};
        f32x4 wa = {0.f,0.f,0.f,0.f};
        ua = MFMA16(a, bu, ua);
        wa = MFMA16(a, bw, wa);
        #pragma unroll
        for (int rg=0;rg<4;rg++){
          int row = mt*16 + q4*4 + rg;
          int col = n0 + r15;
          u_[(chk*32 + row)*256 + col] = f2bf(ua[rg]);
          w_[(chk*32 + row)*256 + col] = f2bf(wa[rg]);
        }
      }
    }
  }
  // attn = tril_incl(qn @ kn^T)
  {
    const int i0 = (wv>>1)*16, j0 = (wv&1)*16;
    f32x4 aacc = {0.f,0.f,0.f,0.f};
    #pragma unroll
    for (int ks=0;ks<8;++ks){
      bf16x8 a = *(const bf16x8*)(qn + (tok0 + i0 + r15)*1024 + h*256 + ks*32 + q4*8);
      bf16x8 bv = *(const bf16x8*)(kn + (tok0 + j0 + r15)*1024 + h*256 + ks*32 + q4*8);
      aacc = MFMA16(a, bv, aacc);
    }
    #pragma unroll
    for (int rg=0;rg<4;rg++){
      int i = i0 + q4*4 + rg, j = j0 + r15;
      attnb[chk*1024 + i*32 + j] = f2bf((i>=j)? aacc[rg] : 0.f);
    }
  }
}

// ---------------- sequential scan; grid = 16 heads x 8 dv-blocks ----------------
// Pipelined: w double-buffered in regs; q/attn/u/k-stage issued at body start;
// S^T mirror + knT double-buffered in LDS -> 2 barriers/chunk, conflict-free staging.
#define SCAN_BODY(NC, WCUR, WNXT, CB, NB) { \
  const int chk_ = bh*128 + (NC); \
  const int ncn_ = ((NC)+1 < 128) ? (NC)+1 : 127; \
  const int chkn_ = bh*128 + ncn_; \
  u16x8 kst[4]; \
  { const u16* kc = kTb + (size_t)chkn_*8192 + tid*32; \
    _Pragma("unroll") for (int v=0;v<4;++v) kst[v] = *(const u16x8*)(kc + v*8); } \
  _Pragma("unroll") for (int ks=0;ks<8;++ks) \
    WNXT[ks] = *(const u16x8*)(w_ + (size_t)(chkn_*32 + tm*16 + r15)*256 + ks*32 + q4*8); \
  u16x8 qv[8]; \
  _Pragma("unroll") for (int ks=0;ks<8;++ks) \
    qv[ks] = *(const u16x8*)(qn + (size_t)(b*4096 + (NC)*32 + tm*16 + r15)*1024 + h*256 + ks*32 + q4*8); \
  u16x8 atv = *(const u16x8*)(attnb + (size_t)chk_*1024 + (tm*16 + r15)*32 + q4*8); \
  u16 uvv[4]; \
  _Pragma("unroll") for (int rg=0;rg<4;++rg) \
    uvv[rg] = u_[(size_t)(chk_*32 + tm*16 + q4*4 + rg)*256 + dv0 + tn*16 + r15]; \
  f32x4 ua = fz, ub2 = fz; \
  _Pragma("unroll") for (int ks=0;ks<8;ks+=2){ \
    bf16x8 s0 = *(const bf16x8*)((const char*)&Sb[CB][tn*16 + r15][0] + ks*64 + q4*16); \
    ua = MFMA16(*(const bf16x8*)&WCUR[ks], s0, ua); \
    bf16x8 s1 = *(const bf16x8*)((const char*)&Sb[CB][tn*16 + r15][0] + (ks+1)*64 + q4*16); \
    ub2 = MFMA16(*(const bf16x8*)&WCUR[ks+1], s1, ub2); } \
  _Pragma("unroll") for (int rg=0;rg<4;++rg){ \
    float uiv = bf2f(uvv[rg]) - ua[rg] - ub2[rg]; \
    uT[tn*16 + r15][tm*16 + q4*4 + rg] = f2bf(uiv); } \
  __syncthreads(); \
  f32x4 oa = fz, ob = fz; \
  _Pragma("unroll") for (int ks=0;ks<8;ks+=2){ \
    bf16x8 s0 = *(const bf16x8*)((const char*)&Sb[CB][tn*16 + r15][0] + ks*64 + q4*16); \
    oa = MFMA16(*(const bf16x8*)&qv[ks], s0, oa); \
    bf16x8 s1 = *(const bf16x8*)((const char*)&Sb[CB][tn*16 + r15][0] + (ks+1)*64 + q4*16); \
    ob = MFMA16(*(const bf16x8*)&qv[ks+1], s1, ob); } \
  { bf16x8 bu = *(const bf16x8*)((const char*)&uT[tn*16 + r15][0] + q4*16); \
    oa = MFMA16(*(const bf16x8*)&atv, bu, oa); } \
  _Pragma("unroll") for (int rg=0;rg<4;++rg) \
    od[(size_t)(b*4096 + (NC)*32 + tm*16 + q4*4 + rg)*1024 + h*256 + dv0 + tn*16 + r15] = f2bf(oa[rg] + ob[rg]); \
  _Pragma("unroll") for (int mt=0;mt<4;++mt){ \
    bf16x8 a = *(const bf16x8*)((const char*)&knT[CB][wv*64 + mt*16 + r15][0] + q4*16); \
    _Pragma("unroll") for (int ntl=0;ntl<2;++ntl){ \
      bf16x8 bu = *(const bf16x8*)((const char*)&uT[ntl*16 + r15][0] + q4*16); \
      Sacc[mt][ntl] = MFMA16(a, bu, Sacc[mt][ntl]); } } \
  _Pragma("unroll") for (int mt=0;mt<4;++mt) \
    _Pragma("unroll") for (int ntl=0;ntl<2;++ntl) \
      _Pragma("unroll") for (int rg=0;rg<4;++rg) \
        Sb[NB][ntl*16 + r15][wv*64 + mt*16 + q4*4 + rg] = f2bf(Sacc[mt][ntl][rg]); \
  _Pragma("unroll") for (int v=0;v<4;++v) *(u16x8*)(&knT[NB][tid][0] + v*8) = kst[v]; \
  __syncthreads(); }

__global__ __launch_bounds__(256,1) void k_scan(
    const u16* __restrict__ qn, const u16* __restrict__ kTb,
    const u16* __restrict__ u_, const u16* __restrict__ w_,
    const u16* __restrict__ attnb, u16* __restrict__ od)
{
  const int bid = blockIdx.x;
  const int bh = bid >> 3;
  const int b = bh >> 2, h = bh & 3;
  const int dv0 = (bid & 7)*32;
  const int tid = threadIdx.x, lane = tid & 63, wv = tid >> 6;
  const int tm = wv >> 1, tn = wv & 1;
  const int r15 = lane & 15, q4 = lane >> 4;

  __shared__ u16 Sb[2][32][264];     // S^T mirror, double buffered
  __shared__ u16 knT[2][256][36];    // k^T chunk, double buffered (row-major, padded)
  __shared__ u16 uT[32][36];         // u_i^T

  for (int i = tid; i < 32*264; i += 256) (&Sb[0][0][0])[i] = 0;
  const f32x4 fz = {0.f,0.f,0.f,0.f};
  f32x4 Sacc[4][2];
  #pragma unroll
  for (int a_=0;a_<4;a_++){
    #pragma unroll
    for (int b_=0;b_<2;b_++) Sacc[a_][b_] = fz;
  }
  // prologue: stage knT[0] (chunk 0), load w-frags for chunk 0
  {
    const u16* kc = kTb + (size_t)(bh*128)*8192 + tid*32;
    u16x8 k0[4];
    #pragma unroll
    for (int v=0;v<4;++v) k0[v] = *(const u16x8*)(kc + v*8);
    #pragma unroll
    for (int v=0;v<4;++v) *(u16x8*)(&knT[0][tid][0] + v*8) = k0[v];
  }
  u16x8 wA[8], wB[8];
  #pragma unroll
  for (int ks=0;ks<8;++ks)
    wA[ks] = *(const u16x8*)(w_ + (size_t)((bh*128)*32 + tm*16 + r15)*256 + ks*32 + q4*8);
  __syncthreads();

  for (int nc = 0; nc < 128; nc += 2){
    SCAN_BODY(nc,   wA, wB, 0, 1)
    SCAN_BODY(nc+1, wB, wA, 1, 0)
  }
}

// ---------------- router features (reads fp32 X directly) ----------------
__global__ __launch_bounds__(256) void k_feats(
    const float* __restrict__ Xf, const u16* __restrict__ lo, const u16* __restrict__ mo,
    const u16* __restrict__ de, const u16* __restrict__ vv, u16* __restrict__ feat)
{
  const int m = blockIdx.x;
  const int tid = threadIdx.x, lane = tid & 63, hh = tid >> 6;
  {
    float4 xv = *(const float4*)(Xf + m*1024 + tid*4);
    u16x4 o; o[0]=f2bf(xv.x); o[1]=f2bf(xv.y); o[2]=f2bf(xv.z); o[3]=f2bf(xv.w);
    *(u16x4*)(feat + m*1088 + tid*4) = o;
  }
  if (tid < 8) feat[m*1088 + 1080 + tid] = 0;
  const int base = m*1024 + hh*256 + lane*4;
  u16x4 a0 = *(const u16x4*)(lo + base);
  u16x4 a1 = *(const u16x4*)(mo + base);
  u16x4 a2 = *(const u16x4*)(de + base);
  u16x4 a3 = *(const u16x4*)(vv + base);
  float s[14];
  #pragma unroll
  for (int i=0;i<14;i++) s[i]=0.f;
  #pragma unroll
  for (int e=0;e<4;e++){
    float L = bf2f(a0[e]), Mm = bf2f(a1[e]), D = bf2f(a2[e]), V = bf2f(a3[e]);
    s[0]+=L; s[1]+=L*L; s[2]+=Mm; s[3]+=Mm*Mm; s[4]+=D; s[5]+=D*D; s[6]+=V; s[7]+=V*V;
    s[8]+=L*Mm; s[9]+=L*D; s[10]+=L*V; s[11]+=Mm*D; s[12]+=Mm*V; s[13]+=D*V;
  }
  #pragma unroll
  for (int i=0;i<14;i++) s[i] = wred(s[i]);
  if (lane == 0){
    const float inv = 1.f/256.f, invv = 1.f/255.f;
    u16* fb = feat + m*1088 + 1024;
    float mn[4] = {s[0]*inv, s[2]*inv, s[4]*inv, s[6]*inv};
    float vr[4] = {(s[1]-256.f*mn[0]*mn[0])*invv, (s[3]-256.f*mn[1]*mn[1])*invv,
                   (s[5]-256.f*mn[2]*mn[2])*invv, (s[7]-256.f*mn[3]*mn[3])*invv};
    #pragma unroll
    for (int i=0;i<4;i++){ fb[(2*i)*4 + hh] = f2bf(mn[i]); fb[(2*i+1)*4 + hh] = f2bf(vr[i]); }
    #pragma unroll
    for (int i=0;i<6;i++) fb[(8+i)*4 + hh] = f2bf(s[8+i]*inv);
  }
}

// ---------------- mix + MixNorm + out RMSNorm ----------------
__global__ __launch_bounds__(256) void k_mix(
    const u16* __restrict__ lo, const u16* __restrict__ mo, const u16* __restrict__ de,
    const u16* __restrict__ vv, const float* __restrict__ p,
    const float* __restrict__ mixw, const float* __restrict__ onw, u16* __restrict__ on)
{
  const int m = blockIdx.x;
  const int tid = threadIdx.x, lane = tid&63, hh = tid>>6;
  const int dbase = lane*4;
  const int base = m*1024 + hh*256 + dbase;
  float4 pv = *(const float4*)(p + m*16 + hh*4);
  u16x4 a0 = *(const u16x4*)(lo + base);
  u16x4 a1 = *(const u16x4*)(mo + base);
  u16x4 a2 = *(const u16x4*)(de + base);
  u16x4 a3 = *(const u16x4*)(vv + base);
  float g[4]; float ss = 0.f;
  #pragma unroll
  for (int e=0;e<4;e++){
    float x = pv.x*bf2f(a0[e]) + pv.y*bf2f(a1[e]) + pv.z*bf2f(a2[e]) + pv.w*bf2f(a3[e]);
    g[e]=x; ss += x*x;
  }
  ss = wred(ss);
  float r1 = rsqrtf(ss*(1.f/256.f) + 1e-5f);
  float ss2 = 0.f;
  #pragma unroll
  for (int e=0;e<4;e++){ g[e] = g[e]*r1*mixw[hh*256 + dbase + e]; ss2 += g[e]*g[e]; }
  ss2 = wred(ss2);
  float r2 = rsqrtf(ss2*(1.f/256.f) + 1e-5f);
  u16x4 o;
  #pragma unroll
  for (int e=0;e<4;e++) o[e] = f2bf(g[e]*r2*onw[dbase + e]);
  *(u16x4*)(on + base) = o;
}

// ==================================================================================
extern "C" void kernel_launch(void* const* d_in, const int* in_sizes, int n_in,
                              void* d_out, int out_size, void* d_ws, size_t ws_size,
                              hipStream_t stream)
{
  const float* X   = (const float*)d_in[0];
  const float* Wq  = (const float*)d_in[1];
  const float* Wk  = (const float*)d_in[2];
  const float* Wv  = (const float*)d_in[3];
  const float* Wb  = (const float*)d_in[4];
  const float* cqw = (const float*)d_in[5];
  const float* ckw = (const float*)d_in[6];
  const float* cvw = (const float*)d_in[7];
  const float* lw  = (const float*)d_in[8];
  const float* mw  = (const float*)d_in[9];
  const float* rw1 = (const float*)d_in[10];
  const float* rb1 = (const float*)d_in[11];
  const float* rw2 = (const float*)d_in[12];
  const float* rb2 = (const float*)d_in[13];
  const float* mixw= (const float*)d_in[14];
  const float* onw = (const float*)d_in[15];
  const float* Wo  = (const float*)d_in[16];

  char* ws = (char*)d_ws;
  const size_t SLOT = 33554432;   // 16384*1024*2
  char* s0 = ws;
  char* s1 = ws + 1*SLOT;
  char* s2 = ws + 2*SLOT;
  char* s3 = ws + 3*SLOT;
  char* s4 = ws + 4*SLOT;
  char* s5 = ws + 5*SLOT;
  char* s6 = ws + 6*SLOT;        // kTb: 2048*256*32*2 = 33,554,432
  char* ext = ws + 7*SLOT;
  u16*   attb  = (u16*)(ext);                       // 4,194,304
  float* pb    = (float*)(ext + 4194304);           // 1,048,576
  float* betab = (float*)(ext + 4194304 + 1048576); // 262,144
  char*  wsp   = ext + 4194304 + 1048576 + 262144;
  u16* Wqt = (u16*)(wsp);
  u16* Wkt = (u16*)(wsp + 2097152);
  u16* Wvt = (u16*)(wsp + 2*2097152);
  u16* Wot = (u16*)(wsp + 3*2097152);
  u16* w1t = (u16*)(wsp + 4*2097152);               // 2176*1088*2
  u16* w2t = (u16*)(wsp + 4*2097152 + 4734976);     // 16*2176*2
  float* b1p = (float*)(wsp + 4*2097152 + 4734976 + 69632);

  // role aliases (lifetime-disjoint)
  u16* Xb    = (u16*)s0;
  u16* rawb  = (u16*)s1;
  u16* qnb   = (u16*)s2;
  u16* knb   = (u16*)s3;
  u16* vpb   = (u16*)s4;
  u16* ub    = (u16*)s0;   // after beta
  u16* wbuf  = (u16*)s1;   // after conv v
  u16* odb   = (u16*)s5;
  u16* kTbp  = (u16*)s6;
  u16* lob   = (u16*)s2;   // after scan
  u16* mob   = (u16*)s3;   // after scan
  u16* featb = (u16*)s0;   // after scan
  u16* onb   = (u16*)s0;   // after router gemm

  // prep
  k_zero<<<1024,256,0,stream>>>(pb, 262144);
  k_cvt<<<16384,256,0,stream>>>(X, Xb, 16777216);
  k_tr<<<dim3(32,32),256,0,stream>>>(Wq, Wqt, 1024,1024,1024,1024);
  k_tr<<<dim3(32,32),256,0,stream>>>(Wk, Wkt, 1024,1024,1024,1024);
  k_tr<<<dim3(32,32),256,0,stream>>>(Wv, Wvt, 1024,1024,1024,1024);
  k_tr<<<dim3(32,32),256,0,stream>>>(Wo, Wot, 1024,1024,1024,1024);
  k_tr<<<dim3(68,34),256,0,stream>>>(rw1, w1t, 1080,2160,1088,2176);
  k_pad_w2t<<<dim3(9,16),256,0,stream>>>(rw2, w2t);
  k_pad_b1<<<9,256,0,stream>>>(rb1, b1p);
  // projections + convs (rawb reused thrice)
  k_gemm<<<dim3(8,128),256,0,stream>>>(Xb, Wqt, rawb, 16384,1024,1024, 0);
  k_conv<<<16384,256,0,stream>>>(rawb, cqw, qnb, 1);
  k_gemm<<<dim3(8,128),256,0,stream>>>(Xb, Wkt, rawb, 16384,1024,1024, 0);
  k_conv<<<16384,256,0,stream>>>(rawb, ckw, knb, 1);
  k_gemm<<<dim3(8,128),256,0,stream>>>(Xb, Wvt, rawb, 16384,1024,1024, 0);
  k_conv<<<16384,256,0,stream>>>(rawb, cvw, vpb, 0);
  k_beta<<<4096,256,0,stream>>>(Xb, Wb, betab);   // last use of Xb
  // delta rule
  k_chunk<<<2048,256,0,stream>>>(qnb, knb, vpb, betab, ub, wbuf, attb);
  k_trk<<<2048,256,0,stream>>>(knb, kTbp);
  k_scan<<<128,256,0,stream>>>(qnb, kTbp, ub, wbuf, attb, odb);
  // local/mid convs (into freed qnb/knb slots)
  k_localmid<<<dim3(128,4,4),256,0,stream>>>(vpb, lw, mw, lob, mob);
  // router (fused h1 gemm + w2 mini-gemm -> atomics into pb)
  k_feats<<<16384,256,0,stream>>>(X, lob, mob, odb, vpb, featb);
  k_gemm_router<<<dim3(17,128),256,0,stream>>>(featb, w1t, b1p, w2t, pb);
  k_softm<<<64,256,0,stream>>>(pb, rb2);
  // mix + output projection
  k_mix<<<16384,256,0,stream>>>(lob, mob, odb, vpb, pb, mixw, onw, onb);
  k_gemm<<<dim3(8,128),256,0,stream>>>(onb, Wot, d_out, 16384,1024,1024, 1);
}

// Round 5
// 1149.335 us; speedup vs baseline: 1.0876x; 1.0876x over previous
//
#include <hip/hip_runtime.h>
#include <cstdint>
#include <cstddef>

typedef unsigned short u16;
typedef __bf16 bf16x8 __attribute__((ext_vector_type(8)));
typedef float    f32x4 __attribute__((ext_vector_type(4)));
typedef unsigned short u16x8 __attribute__((ext_vector_type(8)));
typedef unsigned short u16x4 __attribute__((ext_vector_type(4)));

#define MFMA16(a,b,c) __builtin_amdgcn_mfma_f32_16x16x32_bf16(a,b,c,0,0,0)

__device__ __forceinline__ float bf2f(u16 u){ return __uint_as_float(((unsigned)u)<<16); }
__device__ __forceinline__ u16 f2bf(float f){
  unsigned x = __float_as_uint(f);
  unsigned r = x + 0x7fffu + ((x>>16)&1u);
  return (u16)(r>>16);
}
__device__ __forceinline__ float wred(float v){
  #pragma unroll
  for (int o=32;o;o>>=1) v += __shfl_xor(v,o,64);
  return v;
}
__device__ __forceinline__ float siluf(float x){ return x/(1.f+__expf(-x)); }

// ---------------- zero a float buffer ----------------
__global__ __launch_bounds__(256) void k_zero(float* __restrict__ p, int n){
  int i = blockIdx.x*256 + threadIdx.x;
  if (i < n) p[i] = 0.f;
}

// ---------------- fp32 -> bf16 convert ----------------
__global__ __launch_bounds__(256) void k_cvt(const float* __restrict__ src,
                                             u16* __restrict__ dst, int n){
  int i = (blockIdx.x*256 + threadIdx.x)*4;
  if (i < n){
    float4 f = *(const float4*)(src + i);
    u16x4 o; o[0]=f2bf(f.x); o[1]=f2bf(f.y); o[2]=f2bf(f.z); o[3]=f2bf(f.w);
    *(u16x4*)(dst + i) = o;
  }
}

// ---------------- transpose + cvt + pad: dst[n][k] = (n<C && k<R) ? src[k][n] : 0
__global__ __launch_bounds__(256) void k_tr(const float* __restrict__ src, u16* __restrict__ dst,
                                            int R, int C, int Rp, int Cp){
  __shared__ float t[32][33];
  int n0 = blockIdx.x*32, k0 = blockIdx.y*32;
  int tx = threadIdx.x & 31, ty = threadIdx.x >> 5;
  #pragma unroll
  for (int j=0;j<4;j++){
    int k = k0 + ty + j*8, nn = n0 + tx;
    t[ty + j*8][tx] = (k < R && nn < C) ? src[k*C + nn] : 0.f;
  }
  __syncthreads();
  #pragma unroll
  for (int j=0;j<4;j++){
    int nn = n0 + ty + j*8, k = k0 + tx;
    dst[nn*Rp + k] = f2bf(t[tx][ty + j*8]);
  }
}

// w2t[j][k] = rw2[k][j], j<16, k<2160 (pad to 2176)
__global__ __launch_bounds__(256) void k_pad_w2t(const float* __restrict__ src, u16* __restrict__ dst){
  int k = blockIdx.x*256 + threadIdx.x;
  int j = blockIdx.y;
  if (k < 2176) dst[j*2176 + k] = (k < 2160) ? f2bf(src[k*16 + j]) : (u16)0;
}
__global__ __launch_bounds__(256) void k_pad_b1(const float* __restrict__ src, float* __restrict__ dst){
  int i = blockIdx.x*256 + threadIdx.x;
  if (i < 2176) dst[i] = (i<2160) ? src[i] : 0.f;
}

// ---------------- per-(bh,chunk) k transpose: kTb[chk][d][tl] = kn[(b,t),(h,d)] ----------------
__global__ __launch_bounds__(256) void k_trk(const u16* __restrict__ kn, u16* __restrict__ kTb){
  __shared__ u16 vs[32][264];
  const int g = blockIdx.x;          // bh*128 + nc
  const int bh = g >> 7, nc = g & 127;
  const int b = bh >> 2, h = bh & 3;
  const int tid = threadIdx.x;
  const int rr = tid >> 3, cb = (tid & 7) * 32;
  const u16* src = kn + (size_t)(b*4096 + nc*32 + rr)*1024 + h*256 + cb;
  #pragma unroll
  for (int v=0; v<4; ++v){
    u16x8 x = *(const u16x8*)(src + v*8);
    *(u16x8*)&vs[rr][cb + v*8] = x;
  }
  __syncthreads();
  u16* dst = kTb + ((size_t)g*256 + tid)*32;
  #pragma unroll
  for (int v=0; v<4; ++v){
    u16x8 o;
    #pragma unroll
    for (int e=0; e<8; e++) o[e] = vs[v*8 + e][tid];
    *(u16x8*)(dst + v*8) = o;
  }
}

// ---------------- bf16 GEMM: C[M,N] = A[M,K] @ Bt[N,K]^T ----------------
__global__ __launch_bounds__(256,2) void k_gemm(
    const u16* __restrict__ A, const u16* __restrict__ Bt, void* __restrict__ Cvp,
    int M, int N, int K, int out_f32)
{
  __shared__ u16 As[2][128*64];
  __shared__ u16 Bs[2][128*64];
  const int tid = threadIdx.x;
  const int lane = tid & 63, wv = tid >> 6;
  const int wm = (wv>>1)*64, wn = (wv&1)*64;
  const int r15 = lane & 15, q4 = lane >> 4;
  const int bm0 = blockIdx.y*128, bn0 = blockIdx.x*128;
  const int srow = tid>>3, sch = tid&7;
  const int nk = K >> 6;

  const f32x4 fz = {0.f,0.f,0.f,0.f};
  f32x4 acc[4][4];
  #pragma unroll
  for (int i=0;i<4;i++){
    #pragma unroll
    for (int j=0;j<4;j++) acc[i][j] = fz;
  }

  { // preload tile 0 into buf 0
    u16x8 ca[4], cb[4];
    #pragma unroll
    for (int i=0;i<4;i++){
      int r = i*32 + srow;
      ca[i] = *(const u16x8*)(A  + (size_t)(bm0+r)*K + sch*8);
      cb[i] = *(const u16x8*)(Bt + (size_t)(bn0+r)*K + sch*8);
    }
    #pragma unroll
    for (int i=0;i<4;i++){
      int r = i*32 + srow;
      int byt = r*128 + ((sch ^ (r&7))*16);
      *(u16x8*)((char*)(&As[0][0]) + byt) = ca[i];
      *(u16x8*)((char*)(&Bs[0][0]) + byt) = cb[i];
    }
  }
  int cur = 0;
  for (int t=0; t<nk; ++t){
    u16x8 na[4], nb[4];
    if (t+1 < nk){
      const int kt = (t+1)<<6;
      #pragma unroll
      for (int i=0;i<4;i++){
        int r = i*32 + srow;
        na[i] = *(const u16x8*)(A  + (size_t)(bm0+r)*K + kt + sch*8);
        nb[i] = *(const u16x8*)(Bt + (size_t)(bn0+r)*K + kt + sch*8);
      }
    }
    __syncthreads();
    const u16* as_ = &As[cur][0];
    const u16* bs_ = &Bs[cur][0];
    #pragma unroll
    for (int kk=0; kk<2; ++kk){
      bf16x8 av[4], bv[4];
      #pragma unroll
      for (int mi=0;mi<4;mi++){
        int row = wm + mi*16 + r15;
        int ch  = kk*4 + q4;
        av[mi] = *(const bf16x8*)((const char*)as_ + row*128 + ((ch ^ (row&7))*16));
      }
      #pragma unroll
      for (int ni=0;ni<4;ni++){
        int row = wn + ni*16 + r15;
        int ch  = kk*4 + q4;
        bv[ni] = *(const bf16x8*)((const char*)bs_ + row*128 + ((ch ^ (row&7))*16));
      }
      #pragma unroll
      for (int mi=0;mi<4;mi++){
        #pragma unroll
        for (int ni=0;ni<4;ni++)
          acc[mi][ni] = MFMA16(av[mi], bv[ni], acc[mi][ni]);
      }
    }
    if (t+1 < nk){
      #pragma unroll
      for (int i=0;i<4;i++){
        int r = i*32 + srow;
        int byt = r*128 + ((sch ^ (r&7))*16);
        *(u16x8*)((char*)(&As[cur^1][0]) + byt) = na[i];
        *(u16x8*)((char*)(&Bs[cur^1][0]) + byt) = nb[i];
      }
    }
    cur ^= 1;
  }
  float* Cf = (float*)Cvp;
  u16*  Cb2 = (u16*)Cvp;
  #pragma unroll
  for (int mi=0;mi<4;mi++){
    #pragma unroll
    for (int ni=0;ni<4;ni++){
      int gr = bm0 + wm + mi*16 + q4*4;
      int gc = bn0 + wn + ni*16 + r15;
      #pragma unroll
      for (int rg=0; rg<4; ++rg){
        float v = acc[mi][ni][rg];
        size_t off = (size_t)(gr+rg)*N + gc;
        if (out_f32) Cf[off] = v; else Cb2[off] = f2bf(v);
      }
    }
  }
}

// ---------------- fused router GEMM: logits += silu(feat@w1+b1) @ w2 ----------------
union SMu {
  struct { u16 As[2][128*64]; u16 Bs[2][128*64]; } g;
  u16 h1s[128][136];
};
__global__ __launch_bounds__(256,2) void k_gemm_router(
    const u16* __restrict__ A, const u16* __restrict__ Bt,
    const float* __restrict__ bias, const u16* __restrict__ w2t,
    float* __restrict__ logits)
{
  __shared__ SMu sm;
  const int tid = threadIdx.x;
  const int lane = tid & 63, wv = tid >> 6;
  const int wm = (wv>>1)*64, wn = (wv&1)*64;
  const int r15 = lane & 15, q4 = lane >> 4;
  const int bm0 = blockIdx.y*128, bn0 = blockIdx.x*128;
  const int srow = tid>>3, sch = tid&7;
  const int K = 1088, nk = 17;

  const f32x4 fz = {0.f,0.f,0.f,0.f};
  f32x4 acc[4][4];
  #pragma unroll
  for (int i=0;i<4;i++){
    #pragma unroll
    for (int j=0;j<4;j++) acc[i][j] = fz;
  }
  {
    u16x8 ca[4], cb[4];
    #pragma unroll
    for (int i=0;i<4;i++){
      int r = i*32 + srow;
      ca[i] = *(const u16x8*)(A  + (size_t)(bm0+r)*K + sch*8);
      cb[i] = *(const u16x8*)(Bt + (size_t)(bn0+r)*K + sch*8);
    }
    #pragma unroll
    for (int i=0;i<4;i++){
      int r = i*32 + srow;
      int byt = r*128 + ((sch ^ (r&7))*16);
      *(u16x8*)((char*)(&sm.g.As[0][0]) + byt) = ca[i];
      *(u16x8*)((char*)(&sm.g.Bs[0][0]) + byt) = cb[i];
    }
  }
  int cur = 0;
  for (int t=0; t<nk; ++t){
    u16x8 na[4], nb[4];
    if (t+1 < nk){
      const int kt = (t+1)<<6;
      #pragma unroll
      for (int i=0;i<4;i++){
        int r = i*32 + srow;
        na[i] = *(const u16x8*)(A  + (size_t)(bm0+r)*K + kt + sch*8);
        nb[i] = *(const u16x8*)(Bt + (size_t)(bn0+r)*K + kt + sch*8);
      }
    }
    __syncthreads();
    const u16* as_ = &sm.g.As[cur][0];
    const u16* bs_ = &sm.g.Bs[cur][0];
    #pragma unroll
    for (int kk=0; kk<2; ++kk){
      bf16x8 av[4], bv[4];
      #pragma unroll
      for (int mi=0;mi<4;mi++){
        int row = wm + mi*16 + r15;
        int ch  = kk*4 + q4;
        av[mi] = *(const bf16x8*)((const char*)as_ + row*128 + ((ch ^ (row&7))*16));
      }
      #pragma unroll
      for (int ni=0;ni<4;ni++){
        int row = wn + ni*16 + r15;
        int ch  = kk*4 + q4;
        bv[ni] = *(const bf16x8*)((const char*)bs_ + row*128 + ((ch ^ (row&7))*16));
      }
      #pragma unroll
      for (int mi=0;mi<4;mi++){
        #pragma unroll
        for (int ni=0;ni<4;ni++)
          acc[mi][ni] = MFMA16(av[mi], bv[ni], acc[mi][ni]);
      }
    }
    if (t+1 < nk){
      #pragma unroll
      for (int i=0;i<4;i++){
        int r = i*32 + srow;
        int byt = r*128 + ((sch ^ (r&7))*16);
        *(u16x8*)((char*)(&sm.g.As[cur^1][0]) + byt) = na[i];
        *(u16x8*)((char*)(&sm.g.Bs[cur^1][0]) + byt) = nb[i];
      }
    }
    cur ^= 1;
  }
  __syncthreads();   // done with As/Bs; reuse as h1s
  #pragma unroll
  for (int mi=0;mi<4;mi++){
    #pragma unroll
    for (int ni=0;ni<4;ni++){
      int lr = wm + mi*16 + q4*4;
      int lc = wn + ni*16 + r15;
      float bv_ = bias[bn0 + lc];
      #pragma unroll
      for (int rg=0; rg<4; ++rg)
        sm.h1s[lr+rg][lc] = f2bf(siluf(acc[mi][ni][rg] + bv_));
    }
  }
  __syncthreads();
  f32x4 lacc[2] = {fz, fz};
  #pragma unroll
  for (int rt=0; rt<2; ++rt){
    #pragma unroll
    for (int ks=0; ks<4; ++ks){
      bf16x8 a = *(const bf16x8*)((const char*)&sm.h1s[wv*32 + rt*16 + r15][0] + ks*64 + q4*16);
      bf16x8 b = *(const bf16x8*)(w2t + r15*2176 + bn0 + ks*32 + q4*8);
      lacc[rt] = MFMA16(a, b, lacc[rt]);
    }
  }
  #pragma unroll
  for (int rt=0; rt<2; ++rt){
    #pragma unroll
    for (int rg=0; rg<4; ++rg){
      int m = bm0 + wv*32 + rt*16 + q4*4 + rg;
      atomicAdd(&logits[m*16 + r15], lacc[rt][rg]);
    }
  }
}

// ---------------- softmax + floor over logits (in place) ----------------
__global__ __launch_bounds__(256) void k_softm(float* __restrict__ p, const float* __restrict__ b2){
  int m = blockIdx.x*256 + threadIdx.x;
  float l[16];
  #pragma unroll
  for (int j=0;j<16;j++) l[j] = p[m*16+j] + b2[j];
  #pragma unroll
  for (int hh=0;hh<4;hh++){
    float l0=l[hh*4+0], l1=l[hh*4+1], l2=l[hh*4+2], l3=l[hh*4+3];
    float mx = fmaxf(fmaxf(l0,l1),fmaxf(l2,l3));
    float e0=__expf(l0-mx), e1=__expf(l1-mx), e2=__expf(l2-mx), e3=__expf(l3-mx);
    float iv = 1.f/(e0+e1+e2+e3);
    p[m*16+hh*4+0]=e0*iv*0.96f+0.01f;
    p[m*16+hh*4+1]=e1*iv*0.96f+0.01f;
    p[m*16+hh*4+2]=e2*iv*0.96f+0.01f;
    p[m*16+hh*4+3]=e3*iv*0.96f+0.01f;
  }
}

// ---------------- beta = sigmoid(X @ Wb) ----------------
__global__ __launch_bounds__(256) void k_beta(const u16* __restrict__ Xb,
                                              const float* __restrict__ Wb,
                                              float* __restrict__ beta){
  int m = blockIdx.x*4 + (threadIdx.x>>6);
  int lane = threadIdx.x & 63;
  float a0=0.f,a1=0.f,a2=0.f,a3=0.f;
  #pragma unroll 4
  for (int i=0;i<16;i++){
    int k = lane + i*64;
    float x = bf2f(Xb[m*1024 + k]);
    float4 wr = *(const float4*)(Wb + k*4);
    a0 += x*wr.x; a1 += x*wr.y; a2 += x*wr.z; a3 += x*wr.w;
  }
  a0 = wred(a0); a1 = wred(a1); a2 = wred(a2); a3 = wred(a3);
  if (lane == 0){
    beta[m*4+0] = 1.f/(1.f+__expf(-a0));
    beta[m*4+1] = 1.f/(1.f+__expf(-a1));
    beta[m*4+2] = 1.f/(1.f+__expf(-a2));
    beta[m*4+3] = 1.f/(1.f+__expf(-a3));
  }
}

// ---------------- causal K=4 depthwise conv + silu (+ per-head l2norm) ----------------
__global__ __launch_bounds__(256) void k_conv(const u16* __restrict__ raw,
                                              const float* __restrict__ cw,
                                              u16* __restrict__ outp, int do_norm){
  const int m = blockIdx.x;
  const int tid = threadIdx.x, lane = tid&63, hh = tid>>6;
  const int l = m & 4095;
  const int cbase = hh*256 + lane*4;
  float x[4][4];
  #pragma unroll
  for (int j=0;j<4;j++){
    if (l >= j){
      u16x4 xv = *(const u16x4*)(raw + (m-j)*1024 + cbase);
      #pragma unroll
      for (int e=0;e<4;e++) x[j][e] = bf2f(xv[e]);
    } else {
      #pragma unroll
      for (int e=0;e<4;e++) x[j][e] = 0.f;
    }
  }
  float y[4]; float ss = 0.f;
  #pragma unroll
  for (int e=0;e<4;e++){
    int c = cbase + e;
    float yy = x[0][e]*cw[c*4+3] + x[1][e]*cw[c*4+2] + x[2][e]*cw[c*4+1] + x[3][e]*cw[c*4+0];
    yy = siluf(yy);
    y[e] = yy; ss += yy*yy;
  }
  if (do_norm){
    ss = wred(ss);
    float sc = rsqrtf(ss + 1e-12f);
    #pragma unroll
    for (int e=0;e<4;e++) y[e] *= sc;
  }
  u16x4 o;
  #pragma unroll
  for (int e=0;e<4;e++) o[e] = f2bf(y[e]);
  *(u16x4*)(outp + m*1024 + cbase) = o;
}

// ---------------- local (K=7) + mid (K=25) depthwise causal convs on v ----------------
__global__ __launch_bounds__(256) void k_localmid(const u16* __restrict__ v,
                                                  const float* __restrict__ lw,
                                                  const float* __restrict__ mw,
                                                  u16* __restrict__ lo, u16* __restrict__ mo){
  __shared__ u16 vs[56][256];
  const int lt0 = blockIdx.x*32;
  const int b = blockIdx.y;
  const int c0 = blockIdx.z*256;
  const int tid = threadIdx.x;
  #pragma unroll
  for (int i=0;i<7;i++){
    int flat = tid + i*256;
    int row = flat >> 5;
    int cc = (flat & 31)*8;
    int tok = lt0 - 24 + row;
    u16x8 val = {0,0,0,0,0,0,0,0};
    if (tok >= 0) val = *(const u16x8*)(v + (b*4096 + tok)*1024 + c0 + cc);
    *(u16x8*)&vs[row][cc] = val;
  }
  __syncthreads();
  const int c = tid;
  float lwr[7], mwr[25];
  #pragma unroll
  for (int i=0;i<7;i++) lwr[i] = lw[(c0+c)*7 + i];
  #pragma unroll
  for (int i=0;i<25;i++) mwr[i] = mw[(c0+c)*25 + i];
  for (int lt=0; lt<32; ++lt){
    float a7=0.f, a25=0.f;
    #pragma unroll
    for (int t=0;t<25;t++) a25 += bf2f(vs[lt+t][c]) * mwr[t];
    #pragma unroll
    for (int t=0;t<7;t++)  a7  += bf2f(vs[18+lt+t][c]) * lwr[t];
    int m = b*4096 + lt0 + lt;
    lo[m*1024 + c0 + c] = f2bf(a7);
    mo[m*1024 + c0 + c] = f2bf(a25);
  }
}

// ---------------- chunk-local: T=(I-A)^-1 ; u=T(vB) ; w=T(kB) ; attn=tril(q k^T) ----------------
__global__ __launch_bounds__(256,2) void k_chunk(
    const u16* __restrict__ qn, const u16* __restrict__ kn, const u16* __restrict__ v,
    const float* __restrict__ beta, u16* __restrict__ u_, u16* __restrict__ w_,
    u16* __restrict__ attnb)
{
  const int chk = blockIdx.x;
  const int nc = chk & 127;
  const int bh = chk >> 7;
  const int b = bh >> 2, h = bh & 3;
  const int tok0 = b*4096 + nc*32;
  const int tid = threadIdx.x, lane = tid&63, wv = tid>>6;
  const int r15 = lane&15, q4 = lane>>4;

  __shared__ u16 kbT[256][40];
  __shared__ u16 vbT[256][40];
  __shared__ float Tm[4][32][33];
  __shared__ u16 Xs[32][40];

  {
    int rr = tid >> 3;
    int cb = (tid & 7)*32;
    float bt = beta[(tok0 + rr)*4 + h];
    const u16* ksrc = kn + (tok0+rr)*1024 + h*256 + cb;
    const u16* vsrc = v  + (tok0+rr)*1024 + h*256 + cb;
    #pragma unroll
    for (int vvv=0; vvv<4; ++vvv){
      u16x8 kx = *(const u16x8*)(ksrc + vvv*8);
      u16x8 vx = *(const u16x8*)(vsrc + vvv*8);
      #pragma unroll
      for (int e=0;e<8;e++){
        kbT[cb + vvv*8 + e][rr] = f2bf(bf2f(kx[e]) * bt);
        vbT[cb + vvv*8 + e][rr] = f2bf(bf2f(vx[e]) * bt);
      }
    }
  }
  {
    const int i0 = (wv>>1)*16, j0 = (wv&1)*16;
    float bi = beta[(tok0 + i0 + r15)*4 + h];
    f32x4 tacc = {0.f,0.f,0.f,0.f};
    #pragma unroll
    for (int ks=0; ks<8; ++ks){
      u16x8 ar = *(const u16x8*)(kn + (tok0 + i0 + r15)*1024 + h*256 + ks*32 + q4*8);
      union { u16x8 u; bf16x8 bf; } au;
      #pragma unroll
      for (int e=0;e<8;e++) au.u[e] = f2bf(bf2f(ar[e]) * bi);
      bf16x8 bv = *(const bf16x8*)(kn + (tok0 + j0 + r15)*1024 + h*256 + ks*32 + q4*8);
      tacc = MFMA16(au.bf, bv, tacc);
    }
    #pragma unroll
    for (int rg=0; rg<4; ++rg){
      int i = i0 + q4*4 + rg, j = j0 + r15;
      float val = (i > j) ? -tacc[rg] : 0.f;
      Tm[0][i][j] = val;
      Tm[2][i][j] = val + ((i==j)?1.f:0.f);
    }
  }
  __syncthreads();
  // (I-A)^-1 = (I+A)(I+A^2)(I+A^4)(I+A^8)(I+A^16)  (A^32 = 0)
  int cbuf = 0, cx = 2;
  const int ii = tid >> 3, jj = (tid&7)*4;
  for (int s=0; s<4; ++s){
    int nb = cbuf^1, nx = cx^1;
    {
      float o0=0.f,o1=0.f,o2=0.f,o3=0.f;
      for (int k=0;k<32;k++){
        float a = Tm[cbuf][ii][k];
        o0 += a*Tm[cbuf][k][jj+0]; o1 += a*Tm[cbuf][k][jj+1];
        o2 += a*Tm[cbuf][k][jj+2]; o3 += a*Tm[cbuf][k][jj+3];
      }
      Tm[nb][ii][jj+0]=o0; Tm[nb][ii][jj+1]=o1; Tm[nb][ii][jj+2]=o2; Tm[nb][ii][jj+3]=o3;
    }
    __syncthreads();
    {
      float o0=Tm[cx][ii][jj+0], o1=Tm[cx][ii][jj+1], o2=Tm[cx][ii][jj+2], o3=Tm[cx][ii][jj+3];
      for (int k=0;k<32;k++){
        float a = Tm[nb][ii][k];
        o0 += a*Tm[cx][k][jj+0]; o1 += a*Tm[cx][k][jj+1];
        o2 += a*Tm[cx][k][jj+2]; o3 += a*Tm[cx][k][jj+3];
      }
      Tm[nx][ii][jj+0]=o0; Tm[nx][ii][jj+1]=o1; Tm[nx][ii][jj+2]=o2; Tm[nx][ii][jj+3]=o3;
    }
    __syncthreads();
    cbuf = nb; cx = nx;
  }
  {
    #pragma unroll
    for (int e=0;e<4;e++) Xs[ii][jj+e] = f2bf(Tm[cx][ii][jj+e]);
  }
  __syncthreads();
  // u = X @ vb ; w = X @ kb
  {
    #pragma unroll
    for (int nt=0; nt<4; ++nt){
      int n0 = wv*64 + nt*16;
      #pragma unroll
      for (int mt=0; mt<2; ++mt){
        bf16x8 a = *(const bf16x8*)((const char*)&Xs[mt*16 + r15][0] + q4*16);
        bf16x8 bu = *(const bf16x8*)((const char*)&vbT[n0 + r15][0] + q4*16);
        bf16x8 bw = *(const bf16x8*)((const char*)&kbT[n0 + r15][0] + q4*16);
        f32x4 ua = {0.f,0.f,0.f,0.f};
        f32x4 wa = {0.f,0.f,0.f,0.f};
        ua = MFMA16(a, bu, ua);
        wa = MFMA16(a, bw, wa);
        #pragma unroll
        for (int rg=0;rg<4;rg++){
          int row = mt*16 + q4*4 + rg;
          int col = n0 + r15;
          u_[(chk*32 + row)*256 + col] = f2bf(ua[rg]);
          w_[(chk*32 + row)*256 + col] = f2bf(wa[rg]);
        }
      }
    }
  }
  // attn = tril_incl(qn @ kn^T)
  {
    const int i0 = (wv>>1)*16, j0 = (wv&1)*16;
    f32x4 aacc = {0.f,0.f,0.f,0.f};
    #pragma unroll
    for (int ks=0;ks<8;++ks){
      bf16x8 a = *(const bf16x8*)(qn + (tok0 + i0 + r15)*1024 + h*256 + ks*32 + q4*8);
      bf16x8 bv = *(const bf16x8*)(kn + (tok0 + j0 + r15)*1024 + h*256 + ks*32 + q4*8);
      aacc = MFMA16(a, bv, aacc);
    }
    #pragma unroll
    for (int rg=0;rg<4;rg++){
      int i = i0 + q4*4 + rg, j = j0 + r15;
      attnb[chk*1024 + i*32 + j] = f2bf((i>=j)? aacc[rg] : 0.f);
    }
  }
}

// ---------------- sequential scan; grid = 16 heads x 8 dv-blocks (XCD-pinned) ----------------
// Latency-optimized: raw barriers (lgkmcnt only, no vmcnt drain), full register
// prefetch one chunk ahead (k/w/attn/u), no knT LDS round-trip, S-frags reused
// for phases A and B, b64-packed LDS writes.
struct ScanCtx { u16x8 kf[4]; u16x8 wf[8]; u16x8 at; u16 uv[4]; };

#define SBAR() do{ asm volatile("s_waitcnt lgkmcnt(0)" ::: "memory"); \
                   __builtin_amdgcn_s_barrier(); \
                   asm volatile("" ::: "memory"); }while(0)

#define SPREF(C, CHK) { \
  const u16* kp = kTb + ((size_t)(CHK)*256 + wv*64 + r15)*32 + q4*8; \
  _Pragma("unroll") for (int mt=0;mt<4;++mt) C.kf[mt] = *(const u16x8*)(kp + mt*512); \
  const u16* wp = w_ + ((size_t)(CHK)*32 + tm*16 + r15)*256 + q4*8; \
  _Pragma("unroll") for (int ks=0;ks<8;++ks) C.wf[ks] = *(const u16x8*)(wp + ks*32); \
  C.at = *(const u16x8*)(attnb + (size_t)(CHK)*1024 + (tm*16 + r15)*32 + q4*8); \
  const u16* up = u_ + ((size_t)(CHK)*32 + tm*16 + q4*4)*256 + dv0 + tn*16 + r15; \
  _Pragma("unroll") for (int rg=0;rg<4;++rg) C.uv[rg] = up[rg*256]; \
}

#define SBODY(C, N, NC, CB, NB) { \
  const int chkn_ = chkbase + (((NC)+1 < 128) ? (NC)+1 : 127); \
  SPREF(N, chkn_); \
  u16x8 qf[8]; \
  { const u16* qp = qn + (size_t)(tokbase + (NC)*32 + tm*16 + r15)*1024 + h*256 + q4*8; \
    _Pragma("unroll") for (int ks=0;ks<8;++ks) qf[ks] = *(const u16x8*)(qp + ks*32); } \
  bf16x8 sf[8]; \
  _Pragma("unroll") for (int ks=0;ks<8;++ks) \
    sf[ks] = *(const bf16x8*)((const char*)&Sb[CB][tn*16 + r15][0] + ks*64 + q4*16); \
  f32x4 ua = fz, ub = fz; \
  _Pragma("unroll") for (int ks=0;ks<8;ks+=2){ \
    ua = MFMA16(*(const bf16x8*)&C.wf[ks],   sf[ks],   ua); \
    ub = MFMA16(*(const bf16x8*)&C.wf[ks+1], sf[ks+1], ub); } \
  { u16x4 pk; \
    _Pragma("unroll") for (int rg=0;rg<4;++rg) pk[rg] = f2bf(bf2f(C.uv[rg]) - ua[rg] - ub[rg]); \
    *(u16x4*)&uT[tn*16 + r15][tm*16 + q4*4] = pk; } \
  SBAR(); \
  bf16x8 bu0 = *(const bf16x8*)((const char*)&uT[r15][0] + q4*16); \
  bf16x8 bu1 = *(const bf16x8*)((const char*)&uT[16 + r15][0] + q4*16); \
  f32x4 oa = fz, ob = fz; \
  _Pragma("unroll") for (int ks=0;ks<8;ks+=2){ \
    oa = MFMA16(*(const bf16x8*)&qf[ks],   sf[ks],   oa); \
    ob = MFMA16(*(const bf16x8*)&qf[ks+1], sf[ks+1], ob); } \
  oa = MFMA16(*(const bf16x8*)&C.at, (tn ? bu1 : bu0), oa); \
  _Pragma("unroll") for (int rg=0;rg<4;++rg) \
    od[(size_t)(tokbase + (NC)*32 + tm*16 + q4*4 + rg)*1024 + h*256 + dv0 + tn*16 + r15] = f2bf(oa[rg] + ob[rg]); \
  _Pragma("unroll") for (int mt=0;mt<4;++mt){ \
    Sacc[mt][0] = MFMA16(*(const bf16x8*)&C.kf[mt], bu0, Sacc[mt][0]); \
    Sacc[mt][1] = MFMA16(*(const bf16x8*)&C.kf[mt], bu1, Sacc[mt][1]); } \
  _Pragma("unroll") for (int mt=0;mt<4;++mt){ \
    _Pragma("unroll") for (int ntl=0;ntl<2;++ntl){ \
      u16x4 pk; \
      _Pragma("unroll") for (int rg=0;rg<4;++rg) pk[rg] = f2bf(Sacc[mt][ntl][rg]); \
      *(u16x4*)&Sb[NB][ntl*16 + r15][wv*64 + mt*16 + q4*4] = pk; } } \
  SBAR(); \
}

__global__ __launch_bounds__(256,1) void k_scan(
    const u16* __restrict__ qn, const u16* __restrict__ kTb,
    const u16* __restrict__ u_, const u16* __restrict__ w_,
    const u16* __restrict__ attnb, u16* __restrict__ od)
{
  const int bid = blockIdx.x;
  // XCD-pinning: all 8 dv-blocks of a bh land on the same XCD (bid%8 round-robin)
  const int bh  = (bid & 7) | (((bid >> 3) & 1) << 3);
  const int dv0 = (bid >> 4) * 32;
  const int b = bh >> 2, h = bh & 3;
  const int tid = threadIdx.x, lane = tid & 63, wv = tid >> 6;
  const int tm = wv >> 1, tn = wv & 1;
  const int r15 = lane & 15, q4 = lane >> 4;
  const int chkbase = bh * 128;
  const int tokbase = b * 4096;

  __shared__ u16 Sb[2][32][264];     // S^T mirror (dv x dk), double buffered
  __shared__ u16 uT[32][40];         // u_i^T (dv x rows)

  for (int i = tid; i < 2*32*264; i += 256) (&Sb[0][0][0])[i] = 0;
  const f32x4 fz = {0.f,0.f,0.f,0.f};
  f32x4 Sacc[4][2];
  #pragma unroll
  for (int a_=0;a_<4;a_++){
    #pragma unroll
    for (int b_=0;b_<2;b_++) Sacc[a_][b_] = fz;
  }
  ScanCtx cA, cB;
  SPREF(cA, chkbase);
  __syncthreads();

  for (int nc = 0; nc < 128; nc += 2){
    SBODY(cA, cB, nc,   0, 1)
    SBODY(cB, cA, nc+1, 1, 0)
  }
}

// ---------------- router features (reads fp32 X directly) ----------------
__global__ __launch_bounds__(256) void k_feats(
    const float* __restrict__ Xf, const u16* __restrict__ lo, const u16* __restrict__ mo,
    const u16* __restrict__ de, const u16* __restrict__ vv, u16* __restrict__ feat)
{
  const int m = blockIdx.x;
  const int tid = threadIdx.x, lane = tid & 63, hh = tid >> 6;
  {
    float4 xv = *(const float4*)(Xf + m*1024 + tid*4);
    u16x4 o; o[0]=f2bf(xv.x); o[1]=f2bf(xv.y); o[2]=f2bf(xv.z); o[3]=f2bf(xv.w);
    *(u16x4*)(feat + m*1088 + tid*4) = o;
  }
  if (tid < 8) feat[m*1088 + 1080 + tid] = 0;
  const int base = m*1024 + hh*256 + lane*4;
  u16x4 a0 = *(const u16x4*)(lo + base);
  u16x4 a1 = *(const u16x4*)(mo + base);
  u16x4 a2 = *(const u16x4*)(de + base);
  u16x4 a3 = *(const u16x4*)(vv + base);
  float s[14];
  #pragma unroll
  for (int i=0;i<14;i++) s[i]=0.f;
  #pragma unroll
  for (int e=0;e<4;e++){
    float L = bf2f(a0[e]), Mm = bf2f(a1[e]), D = bf2f(a2[e]), V = bf2f(a3[e]);
    s[0]+=L; s[1]+=L*L; s[2]+=Mm; s[3]+=Mm*Mm; s[4]+=D; s[5]+=D*D; s[6]+=V; s[7]+=V*V;
    s[8]+=L*Mm; s[9]+=L*D; s[10]+=L*V; s[11]+=Mm*D; s[12]+=Mm*V; s[13]+=D*V;
  }
  #pragma unroll
  for (int i=0;i<14;i++) s[i] = wred(s[i]);
  if (lane == 0){
    const float inv = 1.f/256.f, invv = 1.f/255.f;
    u16* fb = feat + m*1088 + 1024;
    float mn[4] = {s[0]*inv, s[2]*inv, s[4]*inv, s[6]*inv};
    float vr[4] = {(s[1]-256.f*mn[0]*mn[0])*invv, (s[3]-256.f*mn[1]*mn[1])*invv,
                   (s[5]-256.f*mn[2]*mn[2])*invv, (s[7]-256.f*mn[3]*mn[3])*invv};
    #pragma unroll
    for (int i=0;i<4;i++){ fb[(2*i)*4 + hh] = f2bf(mn[i]); fb[(2*i+1)*4 + hh] = f2bf(vr[i]); }
    #pragma unroll
    for (int i=0;i<6;i++) fb[(8+i)*4 + hh] = f2bf(s[8+i]*inv);
  }
}

// ---------------- mix + MixNorm + out RMSNorm ----------------
__global__ __launch_bounds__(256) void k_mix(
    const u16* __restrict__ lo, const u16* __restrict__ mo, const u16* __restrict__ de,
    const u16* __restrict__ vv, const float* __restrict__ p,
    const float* __restrict__ mixw, const float* __restrict__ onw, u16* __restrict__ on)
{
  const int m = blockIdx.x;
  const int tid = threadIdx.x, lane = tid&63, hh = tid>>6;
  const int dbase = lane*4;
  const int base = m*1024 + hh*256 + dbase;
  float4 pv = *(const float4*)(p + m*16 + hh*4);
  u16x4 a0 = *(const u16x4*)(lo + base);
  u16x4 a1 = *(const u16x4*)(mo + base);
  u16x4 a2 = *(const u16x4*)(de + base);
  u16x4 a3 = *(const u16x4*)(vv + base);
  float g[4]; float ss = 0.f;
  #pragma unroll
  for (int e=0;e<4;e++){
    float x = pv.x*bf2f(a0[e]) + pv.y*bf2f(a1[e]) + pv.z*bf2f(a2[e]) + pv.w*bf2f(a3[e]);
    g[e]=x; ss += x*x;
  }
  ss = wred(ss);
  float r1 = rsqrtf(ss*(1.f/256.f) + 1e-5f);
  float ss2 = 0.f;
  #pragma unroll
  for (int e=0;e<4;e++){ g[e] = g[e]*r1*mixw[hh*256 + dbase + e]; ss2 += g[e]*g[e]; }
  ss2 = wred(ss2);
  float r2 = rsqrtf(ss2*(1.f/256.f) + 1e-5f);
  u16x4 o;
  #pragma unroll
  for (int e=0;e<4;e++) o[e] = f2bf(g[e]*r2*onw[dbase + e]);
  *(u16x4*)(on + base) = o;
}

// ==================================================================================
extern "C" void kernel_launch(void* const* d_in, const int* in_sizes, int n_in,
                              void* d_out, int out_size, void* d_ws, size_t ws_size,
                              hipStream_t stream)
{
  const float* X   = (const float*)d_in[0];
  const float* Wq  = (const float*)d_in[1];
  const float* Wk  = (const float*)d_in[2];
  const float* Wv  = (const float*)d_in[3];
  const float* Wb  = (const float*)d_in[4];
  const float* cqw = (const float*)d_in[5];
  const float* ckw = (const float*)d_in[6];
  const float* cvw = (const float*)d_in[7];
  const float* lw  = (const float*)d_in[8];
  const float* mw  = (const float*)d_in[9];
  const float* rw1 = (const float*)d_in[10];
  const float* rb1 = (const float*)d_in[11];
  const float* rw2 = (const float*)d_in[12];
  const float* rb2 = (const float*)d_in[13];
  const float* mixw= (const float*)d_in[14];
  const float* onw = (const float*)d_in[15];
  const float* Wo  = (const float*)d_in[16];

  char* ws = (char*)d_ws;
  const size_t SLOT = 33554432;   // 16384*1024*2
  char* s0 = ws;
  char* s1 = ws + 1*SLOT;
  char* s2 = ws + 2*SLOT;
  char* s3 = ws + 3*SLOT;
  char* s4 = ws + 4*SLOT;
  char* s5 = ws + 5*SLOT;
  char* s6 = ws + 6*SLOT;        // kTb: 2048*256*32*2 = 33,554,432
  char* ext = ws + 7*SLOT;
  u16*   attb  = (u16*)(ext);                       // 4,194,304
  float* pb    = (float*)(ext + 4194304);           // 1,048,576
  float* betab = (float*)(ext + 4194304 + 1048576); // 262,144
  char*  wsp   = ext + 4194304 + 1048576 + 262144;
  u16* Wqt = (u16*)(wsp);
  u16* Wkt = (u16*)(wsp + 2097152);
  u16* Wvt = (u16*)(wsp + 2*2097152);
  u16* Wot = (u16*)(wsp + 3*2097152);
  u16* w1t = (u16*)(wsp + 4*2097152);               // 2176*1088*2
  u16* w2t = (u16*)(wsp + 4*2097152 + 4734976);     // 16*2176*2
  float* b1p = (float*)(wsp + 4*2097152 + 4734976 + 69632);

  // role aliases (lifetime-disjoint)
  u16* Xb    = (u16*)s0;
  u16* rawb  = (u16*)s1;
  u16* qnb   = (u16*)s2;
  u16* knb   = (u16*)s3;
  u16* vpb   = (u16*)s4;
  u16* ub    = (u16*)s0;   // after beta
  u16* wbuf  = (u16*)s1;   // after conv v
  u16* odb   = (u16*)s5;
  u16* kTbp  = (u16*)s6;
  u16* lob   = (u16*)s2;   // after scan
  u16* mob   = (u16*)s3;   // after scan
  u16* featb = (u16*)s0;   // after scan
  u16* onb   = (u16*)s0;   // after router gemm

  // prep
  k_zero<<<1024,256,0,stream>>>(pb, 262144);
  k_cvt<<<16384,256,0,stream>>>(X, Xb, 16777216);
  k_tr<<<dim3(32,32),256,0,stream>>>(Wq, Wqt, 1024,1024,1024,1024);
  k_tr<<<dim3(32,32),256,0,stream>>>(Wk, Wkt, 1024,1024,1024,1024);
  k_tr<<<dim3(32,32),256,0,stream>>>(Wv, Wvt, 1024,1024,1024,1024);
  k_tr<<<dim3(32,32),256,0,stream>>>(Wo, Wot, 1024,1024,1024,1024);
  k_tr<<<dim3(68,34),256,0,stream>>>(rw1, w1t, 1080,2160,1088,2176);
  k_pad_w2t<<<dim3(9,16),256,0,stream>>>(rw2, w2t);
  k_pad_b1<<<9,256,0,stream>>>(rb1, b1p);
  // projections + convs (rawb reused thrice)
  k_gemm<<<dim3(8,128),256,0,stream>>>(Xb, Wqt, rawb, 16384,1024,1024, 0);
  k_conv<<<16384,256,0,stream>>>(rawb, cqw, qnb, 1);
  k_gemm<<<dim3(8,128),256,0,stream>>>(Xb, Wkt, rawb, 16384,1024,1024, 0);
  k_conv<<<16384,256,0,stream>>>(rawb, ckw, knb, 1);
  k_gemm<<<dim3(8,128),256,0,stream>>>(Xb, Wvt, rawb, 16384,1024,1024, 0);
  k_conv<<<16384,256,0,stream>>>(rawb, cvw, vpb, 0);
  k_beta<<<4096,256,0,stream>>>(Xb, Wb, betab);   // last use of Xb
  // delta rule
  k_chunk<<<2048,256,0,stream>>>(qnb, knb, vpb, betab, ub, wbuf, attb);
  k_trk<<<2048,256,0,stream>>>(knb, kTbp);
  k_scan<<<128,256,0,stream>>>(qnb, kTbp, ub, wbuf, attb, odb);
  // local/mid convs (into freed qnb/knb slots)
  k_localmid<<<dim3(128,4,4),256,0,stream>>>(vpb, lw, mw, lob, mob);
  // router (fused h1 gemm + w2 mini-gemm -> atomics into pb)
  k_feats<<<16384,256,0,stream>>>(X, lob, mob, odb, vpb, featb);
  k_gemm_router<<<dim3(17,128),256,0,stream>>>(featb, w1t, b1p, w2t, pb);
  k_softm<<<64,256,0,stream>>>(pb, rb2);
  // mix + output projection
  k_mix<<<16384,256,0,stream>>>(lob, mob, odb, vpb, pb, mixw, onw, onb);
  k_gemm<<<dim3(8,128),256,0,stream>>>(onb, Wot, d_out, 16384,1024,1024, 1);
}

// Round 6
// 1083.716 us; speedup vs baseline: 1.1534x; 1.0605x over previous
//
#include <hip/hip_runtime.h>
#include <cstdint>
#include <cstddef>

typedef unsigned short u16;
typedef __bf16 bf16x8 __attribute__((ext_vector_type(8)));
typedef float    f32x4 __attribute__((ext_vector_type(4)));
typedef unsigned short u16x8 __attribute__((ext_vector_type(8)));
typedef unsigned short u16x4 __attribute__((ext_vector_type(4)));

#define MFMA16(a,b,c) __builtin_amdgcn_mfma_f32_16x16x32_bf16(a,b,c,0,0,0)

__device__ __forceinline__ float bf2f(u16 u){ return __uint_as_float(((unsigned)u)<<16); }
__device__ __forceinline__ u16 f2bf(float f){
  unsigned x = __float_as_uint(f);
  unsigned r = x + 0x7fffu + ((x>>16)&1u);
  return (u16)(r>>16);
}
__device__ __forceinline__ float wred(float v){
  #pragma unroll
  for (int o=32;o;o>>=1) v += __shfl_xor(v,o,64);
  return v;
}
__device__ __forceinline__ float siluf(float x){ return x/(1.f+__expf(-x)); }

// ---------------- zero a float buffer ----------------
__global__ __launch_bounds__(256) void k_zero(float* __restrict__ p, int n){
  int i = blockIdx.x*256 + threadIdx.x;
  if (i < n) p[i] = 0.f;
}

// ---------------- fp32 -> bf16 convert ----------------
__global__ __launch_bounds__(256) void k_cvt(const float* __restrict__ src,
                                             u16* __restrict__ dst, int n){
  int i = (blockIdx.x*256 + threadIdx.x)*4;
  if (i < n){
    float4 f = *(const float4*)(src + i);
    u16x4 o; o[0]=f2bf(f.x); o[1]=f2bf(f.y); o[2]=f2bf(f.z); o[3]=f2bf(f.w);
    *(u16x4*)(dst + i) = o;
  }
}

// ---------------- transpose + cvt + pad ----------------
__global__ __launch_bounds__(256) void k_tr(const float* __restrict__ src, u16* __restrict__ dst,
                                            int R, int C, int Rp, int Cp){
  __shared__ float t[32][33];
  int n0 = blockIdx.x*32, k0 = blockIdx.y*32;
  int tx = threadIdx.x & 31, ty = threadIdx.x >> 5;
  #pragma unroll
  for (int j=0;j<4;j++){
    int k = k0 + ty + j*8, nn = n0 + tx;
    t[ty + j*8][tx] = (k < R && nn < C) ? src[k*C + nn] : 0.f;
  }
  __syncthreads();
  #pragma unroll
  for (int j=0;j<4;j++){
    int nn = n0 + ty + j*8, k = k0 + tx;
    dst[nn*Rp + k] = f2bf(t[tx][ty + j*8]);
  }
}

__global__ __launch_bounds__(256) void k_pad_w2t(const float* __restrict__ src, u16* __restrict__ dst){
  int k = blockIdx.x*256 + threadIdx.x;
  int j = blockIdx.y;
  if (k < 2176) dst[j*2176 + k] = (k < 2160) ? f2bf(src[k*16 + j]) : (u16)0;
}
__global__ __launch_bounds__(256) void k_pad_b1(const float* __restrict__ src, float* __restrict__ dst){
  int i = blockIdx.x*256 + threadIdx.x;
  if (i < 2176) dst[i] = (i<2160) ? src[i] : 0.f;
}

// ---------------- per-(bh,chunk32) k transpose ----------------
__global__ __launch_bounds__(256) void k_trk(const u16* __restrict__ kn, u16* __restrict__ kTb){
  __shared__ u16 vs[32][264];
  const int g = blockIdx.x;          // bh*128 + nc
  const int bh = g >> 7, nc = g & 127;
  const int b = bh >> 2, h = bh & 3;
  const int tid = threadIdx.x;
  const int rr = tid >> 3, cb = (tid & 7) * 32;
  const u16* src = kn + (size_t)(b*4096 + nc*32 + rr)*1024 + h*256 + cb;
  #pragma unroll
  for (int v=0; v<4; ++v){
    u16x8 x = *(const u16x8*)(src + v*8);
    *(u16x8*)&vs[rr][cb + v*8] = x;
  }
  __syncthreads();
  u16* dst = kTb + ((size_t)g*256 + tid)*32;
  #pragma unroll
  for (int v=0; v<4; ++v){
    u16x8 o;
    #pragma unroll
    for (int e=0; e<8; e++) o[e] = vs[v*8 + e][tid];
    *(u16x8*)(dst + v*8) = o;
  }
}

// ---------------- bf16 GEMM: C[M,N] = A[M,K] @ Bt[N,K]^T ----------------
__global__ __launch_bounds__(256,2) void k_gemm(
    const u16* __restrict__ A, const u16* __restrict__ Bt, void* __restrict__ Cvp,
    int M, int N, int K, int out_f32)
{
  __shared__ u16 As[2][128*64];
  __shared__ u16 Bs[2][128*64];
  const int tid = threadIdx.x;
  const int lane = tid & 63, wv = tid >> 6;
  const int wm = (wv>>1)*64, wn = (wv&1)*64;
  const int r15 = lane & 15, q4 = lane >> 4;
  const int bm0 = blockIdx.y*128, bn0 = blockIdx.x*128;
  const int srow = tid>>3, sch = tid&7;
  const int nk = K >> 6;

  const f32x4 fz = {0.f,0.f,0.f,0.f};
  f32x4 acc[4][4];
  #pragma unroll
  for (int i=0;i<4;i++){
    #pragma unroll
    for (int j=0;j<4;j++) acc[i][j] = fz;
  }
  {
    u16x8 ca[4], cb[4];
    #pragma unroll
    for (int i=0;i<4;i++){
      int r = i*32 + srow;
      ca[i] = *(const u16x8*)(A  + (size_t)(bm0+r)*K + sch*8);
      cb[i] = *(const u16x8*)(Bt + (size_t)(bn0+r)*K + sch*8);
    }
    #pragma unroll
    for (int i=0;i<4;i++){
      int r = i*32 + srow;
      int byt = r*128 + ((sch ^ (r&7))*16);
      *(u16x8*)((char*)(&As[0][0]) + byt) = ca[i];
      *(u16x8*)((char*)(&Bs[0][0]) + byt) = cb[i];
    }
  }
  int cur = 0;
  for (int t=0; t<nk; ++t){
    u16x8 na[4], nb[4];
    if (t+1 < nk){
      const int kt = (t+1)<<6;
      #pragma unroll
      for (int i=0;i<4;i++){
        int r = i*32 + srow;
        na[i] = *(const u16x8*)(A  + (size_t)(bm0+r)*K + kt + sch*8);
        nb[i] = *(const u16x8*)(Bt + (size_t)(bn0+r)*K + kt + sch*8);
      }
    }
    __syncthreads();
    const u16* as_ = &As[cur][0];
    const u16* bs_ = &Bs[cur][0];
    #pragma unroll
    for (int kk=0; kk<2; ++kk){
      bf16x8 av[4], bv[4];
      #pragma unroll
      for (int mi=0;mi<4;mi++){
        int row = wm + mi*16 + r15;
        int ch  = kk*4 + q4;
        av[mi] = *(const bf16x8*)((const char*)as_ + row*128 + ((ch ^ (row&7))*16));
      }
      #pragma unroll
      for (int ni=0;ni<4;ni++){
        int row = wn + ni*16 + r15;
        int ch  = kk*4 + q4;
        bv[ni] = *(const bf16x8*)((const char*)bs_ + row*128 + ((ch ^ (row&7))*16));
      }
      #pragma unroll
      for (int mi=0;mi<4;mi++){
        #pragma unroll
        for (int ni=0;ni<4;ni++)
          acc[mi][ni] = MFMA16(av[mi], bv[ni], acc[mi][ni]);
      }
    }
    if (t+1 < nk){
      #pragma unroll
      for (int i=0;i<4;i++){
        int r = i*32 + srow;
        int byt = r*128 + ((sch ^ (r&7))*16);
        *(u16x8*)((char*)(&As[cur^1][0]) + byt) = na[i];
        *(u16x8*)((char*)(&Bs[cur^1][0]) + byt) = nb[i];
      }
    }
    cur ^= 1;
  }
  float* Cf = (float*)Cvp;
  u16*  Cb2 = (u16*)Cvp;
  #pragma unroll
  for (int mi=0;mi<4;mi++){
    #pragma unroll
    for (int ni=0;ni<4;ni++){
      int gr = bm0 + wm + mi*16 + q4*4;
      int gc = bn0 + wn + ni*16 + r15;
      #pragma unroll
      for (int rg=0; rg<4; ++rg){
        float v = acc[mi][ni][rg];
        size_t off = (size_t)(gr+rg)*N + gc;
        if (out_f32) Cf[off] = v; else Cb2[off] = f2bf(v);
      }
    }
  }
}

// ---------------- fused router GEMM ----------------
union SMu {
  struct { u16 As[2][128*64]; u16 Bs[2][128*64]; } g;
  u16 h1s[128][136];
};
__global__ __launch_bounds__(256,2) void k_gemm_router(
    const u16* __restrict__ A, const u16* __restrict__ Bt,
    const float* __restrict__ bias, const u16* __restrict__ w2t,
    float* __restrict__ logits)
{
  __shared__ SMu sm;
  const int tid = threadIdx.x;
  const int lane = tid & 63, wv = tid >> 6;
  const int wm = (wv>>1)*64, wn = (wv&1)*64;
  const int r15 = lane & 15, q4 = lane >> 4;
  const int bm0 = blockIdx.y*128, bn0 = blockIdx.x*128;
  const int srow = tid>>3, sch = tid&7;
  const int K = 1088, nk = 17;

  const f32x4 fz = {0.f,0.f,0.f,0.f};
  f32x4 acc[4][4];
  #pragma unroll
  for (int i=0;i<4;i++){
    #pragma unroll
    for (int j=0;j<4;j++) acc[i][j] = fz;
  }
  {
    u16x8 ca[4], cb[4];
    #pragma unroll
    for (int i=0;i<4;i++){
      int r = i*32 + srow;
      ca[i] = *(const u16x8*)(A  + (size_t)(bm0+r)*K + sch*8);
      cb[i] = *(const u16x8*)(Bt + (size_t)(bn0+r)*K + sch*8);
    }
    #pragma unroll
    for (int i=0;i<4;i++){
      int r = i*32 + srow;
      int byt = r*128 + ((sch ^ (r&7))*16);
      *(u16x8*)((char*)(&sm.g.As[0][0]) + byt) = ca[i];
      *(u16x8*)((char*)(&sm.g.Bs[0][0]) + byt) = cb[i];
    }
  }
  int cur = 0;
  for (int t=0; t<nk; ++t){
    u16x8 na[4], nb[4];
    if (t+1 < nk){
      const int kt = (t+1)<<6;
      #pragma unroll
      for (int i=0;i<4;i++){
        int r = i*32 + srow;
        na[i] = *(const u16x8*)(A  + (size_t)(bm0+r)*K + kt + sch*8);
        nb[i] = *(const u16x8*)(Bt + (size_t)(bn0+r)*K + kt + sch*8);
      }
    }
    __syncthreads();
    const u16* as_ = &sm.g.As[cur][0];
    const u16* bs_ = &sm.g.Bs[cur][0];
    #pragma unroll
    for (int kk=0; kk<2; ++kk){
      bf16x8 av[4], bv[4];
      #pragma unroll
      for (int mi=0;mi<4;mi++){
        int row = wm + mi*16 + r15;
        int ch  = kk*4 + q4;
        av[mi] = *(const bf16x8*)((const char*)as_ + row*128 + ((ch ^ (row&7))*16));
      }
      #pragma unroll
      for (int ni=0;ni<4;ni++){
        int row = wn + ni*16 + r15;
        int ch  = kk*4 + q4;
        bv[ni] = *(const bf16x8*)((const char*)bs_ + row*128 + ((ch ^ (row&7))*16));
      }
      #pragma unroll
      for (int mi=0;mi<4;mi++){
        #pragma unroll
        for (int ni=0;ni<4;ni++)
          acc[mi][ni] = MFMA16(av[mi], bv[ni], acc[mi][ni]);
      }
    }
    if (t+1 < nk){
      #pragma unroll
      for (int i=0;i<4;i++){
        int r = i*32 + srow;
        int byt = r*128 + ((sch ^ (r&7))*16);
        *(u16x8*)((char*)(&sm.g.As[cur^1][0]) + byt) = na[i];
        *(u16x8*)((char*)(&sm.g.Bs[cur^1][0]) + byt) = nb[i];
      }
    }
    cur ^= 1;
  }
  __syncthreads();
  #pragma unroll
  for (int mi=0;mi<4;mi++){
    #pragma unroll
    for (int ni=0;ni<4;ni++){
      int lr = wm + mi*16 + q4*4;
      int lc = wn + ni*16 + r15;
      float bv_ = bias[bn0 + lc];
      #pragma unroll
      for (int rg=0; rg<4; ++rg)
        sm.h1s[lr+rg][lc] = f2bf(siluf(acc[mi][ni][rg] + bv_));
    }
  }
  __syncthreads();
  f32x4 lacc[2] = {fz, fz};
  #pragma unroll
  for (int rt=0; rt<2; ++rt){
    #pragma unroll
    for (int ks=0; ks<4; ++ks){
      bf16x8 a = *(const bf16x8*)((const char*)&sm.h1s[wv*32 + rt*16 + r15][0] + ks*64 + q4*16);
      bf16x8 b = *(const bf16x8*)(w2t + r15*2176 + bn0 + ks*32 + q4*8);
      lacc[rt] = MFMA16(a, b, lacc[rt]);
    }
  }
  #pragma unroll
  for (int rt=0; rt<2; ++rt){
    #pragma unroll
    for (int rg=0; rg<4; ++rg){
      int m = bm0 + wv*32 + rt*16 + q4*4 + rg;
      atomicAdd(&logits[m*16 + r15], lacc[rt][rg]);
    }
  }
}

// ---------------- softmax + floor ----------------
__global__ __launch_bounds__(256) void k_softm(float* __restrict__ p, const float* __restrict__ b2){
  int m = blockIdx.x*256 + threadIdx.x;
  float l[16];
  #pragma unroll
  for (int j=0;j<16;j++) l[j] = p[m*16+j] + b2[j];
  #pragma unroll
  for (int hh=0;hh<4;hh++){
    float l0=l[hh*4+0], l1=l[hh*4+1], l2=l[hh*4+2], l3=l[hh*4+3];
    float mx = fmaxf(fmaxf(l0,l1),fmaxf(l2,l3));
    float e0=__expf(l0-mx), e1=__expf(l1-mx), e2=__expf(l2-mx), e3=__expf(l3-mx);
    float iv = 1.f/(e0+e1+e2+e3);
    p[m*16+hh*4+0]=e0*iv*0.96f+0.01f;
    p[m*16+hh*4+1]=e1*iv*0.96f+0.01f;
    p[m*16+hh*4+2]=e2*iv*0.96f+0.01f;
    p[m*16+hh*4+3]=e3*iv*0.96f+0.01f;
  }
}

// ---------------- beta = sigmoid(X @ Wb) ----------------
__global__ __launch_bounds__(256) void k_beta(const u16* __restrict__ Xb,
                                              const float* __restrict__ Wb,
                                              float* __restrict__ beta){
  int m = blockIdx.x*4 + (threadIdx.x>>6);
  int lane = threadIdx.x & 63;
  float a0=0.f,a1=0.f,a2=0.f,a3=0.f;
  #pragma unroll 4
  for (int i=0;i<16;i++){
    int k = lane + i*64;
    float x = bf2f(Xb[m*1024 + k]);
    float4 wr = *(const float4*)(Wb + k*4);
    a0 += x*wr.x; a1 += x*wr.y; a2 += x*wr.z; a3 += x*wr.w;
  }
  a0 = wred(a0); a1 = wred(a1); a2 = wred(a2); a3 = wred(a3);
  if (lane == 0){
    beta[m*4+0] = 1.f/(1.f+__expf(-a0));
    beta[m*4+1] = 1.f/(1.f+__expf(-a1));
    beta[m*4+2] = 1.f/(1.f+__expf(-a2));
    beta[m*4+3] = 1.f/(1.f+__expf(-a3));
  }
}

// ---------------- causal K=4 depthwise conv + silu (+ l2norm) ----------------
__global__ __launch_bounds__(256) void k_conv(const u16* __restrict__ raw,
                                              const float* __restrict__ cw,
                                              u16* __restrict__ outp, int do_norm){
  const int m = blockIdx.x;
  const int tid = threadIdx.x, lane = tid&63, hh = tid>>6;
  const int l = m & 4095;
  const int cbase = hh*256 + lane*4;
  float x[4][4];
  #pragma unroll
  for (int j=0;j<4;j++){
    if (l >= j){
      u16x4 xv = *(const u16x4*)(raw + (m-j)*1024 + cbase);
      #pragma unroll
      for (int e=0;e<4;e++) x[j][e] = bf2f(xv[e]);
    } else {
      #pragma unroll
      for (int e=0;e<4;e++) x[j][e] = 0.f;
    }
  }
  float y[4]; float ss = 0.f;
  #pragma unroll
  for (int e=0;e<4;e++){
    int c = cbase + e;
    float yy = x[0][e]*cw[c*4+3] + x[1][e]*cw[c*4+2] + x[2][e]*cw[c*4+1] + x[3][e]*cw[c*4+0];
    yy = siluf(yy);
    y[e] = yy; ss += yy*yy;
  }
  if (do_norm){
    ss = wred(ss);
    float sc = rsqrtf(ss + 1e-12f);
    #pragma unroll
    for (int e=0;e<4;e++) y[e] *= sc;
  }
  u16x4 o;
  #pragma unroll
  for (int e=0;e<4;e++) o[e] = f2bf(y[e]);
  *(u16x4*)(outp + m*1024 + cbase) = o;
}

// ---------------- local/mid depthwise causal convs ----------------
__global__ __launch_bounds__(256) void k_localmid(const u16* __restrict__ v,
                                                  const float* __restrict__ lw,
                                                  const float* __restrict__ mw,
                                                  u16* __restrict__ lo, u16* __restrict__ mo){
  __shared__ u16 vs[56][256];
  const int lt0 = blockIdx.x*32;
  const int b = blockIdx.y;
  const int c0 = blockIdx.z*256;
  const int tid = threadIdx.x;
  #pragma unroll
  for (int i=0;i<7;i++){
    int flat = tid + i*256;
    int row = flat >> 5;
    int cc = (flat & 31)*8;
    int tok = lt0 - 24 + row;
    u16x8 val = {0,0,0,0,0,0,0,0};
    if (tok >= 0) val = *(const u16x8*)(v + (b*4096 + tok)*1024 + c0 + cc);
    *(u16x8*)&vs[row][cc] = val;
  }
  __syncthreads();
  const int c = tid;
  float lwr[7], mwr[25];
  #pragma unroll
  for (int i=0;i<7;i++) lwr[i] = lw[(c0+c)*7 + i];
  #pragma unroll
  for (int i=0;i<25;i++) mwr[i] = mw[(c0+c)*25 + i];
  for (int lt=0; lt<32; ++lt){
    float a7=0.f, a25=0.f;
    #pragma unroll
    for (int t=0;t<25;t++) a25 += bf2f(vs[lt+t][c]) * mwr[t];
    #pragma unroll
    for (int t=0;t<7;t++)  a7  += bf2f(vs[18+lt+t][c]) * lwr[t];
    int m = b*4096 + lt0 + lt;
    lo[m*1024 + c0 + c] = f2bf(a7);
    mo[m*1024 + c0 + c] = f2bf(a25);
  }
}

// ---------------- chunk-local (32): T=(I-A)^-1 ; u=T(vB) ; w=T(kB) ----------------
__global__ __launch_bounds__(256,2) void k_chunk(
    const u16* __restrict__ qn, const u16* __restrict__ kn, const u16* __restrict__ v,
    const float* __restrict__ beta, u16* __restrict__ u_, u16* __restrict__ w_)
{
  const int chk = blockIdx.x;
  const int nc = chk & 127;
  const int bh = chk >> 7;
  const int b = bh >> 2, h = bh & 3;
  const int tok0 = b*4096 + nc*32;
  const int tid = threadIdx.x, lane = tid&63, wv = tid>>6;
  const int r15 = lane&15, q4 = lane>>4;

  __shared__ u16 kbT[256][40];
  __shared__ u16 vbT[256][40];
  __shared__ float Tm[4][32][33];
  __shared__ u16 Xs[32][40];

  {
    int rr = tid >> 3;
    int cb = (tid & 7)*32;
    float bt = beta[(tok0 + rr)*4 + h];
    const u16* ksrc = kn + (tok0+rr)*1024 + h*256 + cb;
    const u16* vsrc = v  + (tok0+rr)*1024 + h*256 + cb;
    #pragma unroll
    for (int vvv=0; vvv<4; ++vvv){
      u16x8 kx = *(const u16x8*)(ksrc + vvv*8);
      u16x8 vx = *(const u16x8*)(vsrc + vvv*8);
      #pragma unroll
      for (int e=0;e<8;e++){
        kbT[cb + vvv*8 + e][rr] = f2bf(bf2f(kx[e]) * bt);
        vbT[cb + vvv*8 + e][rr] = f2bf(bf2f(vx[e]) * bt);
      }
    }
  }
  {
    const int i0 = (wv>>1)*16, j0 = (wv&1)*16;
    float bi = beta[(tok0 + i0 + r15)*4 + h];
    f32x4 tacc = {0.f,0.f,0.f,0.f};
    #pragma unroll
    for (int ks=0; ks<8; ++ks){
      u16x8 ar = *(const u16x8*)(kn + (tok0 + i0 + r15)*1024 + h*256 + ks*32 + q4*8);
      union { u16x8 u; bf16x8 bf; } au;
      #pragma unroll
      for (int e=0;e<8;e++) au.u[e] = f2bf(bf2f(ar[e]) * bi);
      bf16x8 bv = *(const bf16x8*)(kn + (tok0 + j0 + r15)*1024 + h*256 + ks*32 + q4*8);
      tacc = MFMA16(au.bf, bv, tacc);
    }
    #pragma unroll
    for (int rg=0; rg<4; ++rg){
      int i = i0 + q4*4 + rg, j = j0 + r15;
      float val = (i > j) ? -tacc[rg] : 0.f;
      Tm[0][i][j] = val;
      Tm[2][i][j] = val + ((i==j)?1.f:0.f);
    }
  }
  __syncthreads();
  int cbuf = 0, cx = 2;
  const int ii = tid >> 3, jj = (tid&7)*4;
  for (int s=0; s<4; ++s){
    int nb = cbuf^1, nx = cx^1;
    {
      float o0=0.f,o1=0.f,o2=0.f,o3=0.f;
      for (int k=0;k<32;k++){
        float a = Tm[cbuf][ii][k];
        o0 += a*Tm[cbuf][k][jj+0]; o1 += a*Tm[cbuf][k][jj+1];
        o2 += a*Tm[cbuf][k][jj+2]; o3 += a*Tm[cbuf][k][jj+3];
      }
      Tm[nb][ii][jj+0]=o0; Tm[nb][ii][jj+1]=o1; Tm[nb][ii][jj+2]=o2; Tm[nb][ii][jj+3]=o3;
    }
    __syncthreads();
    {
      float o0=Tm[cx][ii][jj+0], o1=Tm[cx][ii][jj+1], o2=Tm[cx][ii][jj+2], o3=Tm[cx][ii][jj+3];
      for (int k=0;k<32;k++){
        float a = Tm[nb][ii][k];
        o0 += a*Tm[cx][k][jj+0]; o1 += a*Tm[cx][k][jj+1];
        o2 += a*Tm[cx][k][jj+2]; o3 += a*Tm[cx][k][jj+3];
      }
      Tm[nx][ii][jj+0]=o0; Tm[nx][ii][jj+1]=o1; Tm[nx][ii][jj+2]=o2; Tm[nx][ii][jj+3]=o3;
    }
    __syncthreads();
    cbuf = nb; cx = nx;
  }
  {
    #pragma unroll
    for (int e=0;e<4;e++) Xs[ii][jj+e] = f2bf(Tm[cx][ii][jj+e]);
  }
  __syncthreads();
  {
    #pragma unroll
    for (int nt=0; nt<4; ++nt){
      int n0 = wv*64 + nt*16;
      #pragma unroll
      for (int mt=0; mt<2; ++mt){
        bf16x8 a = *(const bf16x8*)((const char*)&Xs[mt*16 + r15][0] + q4*16);
        bf16x8 bu = *(const bf16x8*)((const char*)&vbT[n0 + r15][0] + q4*16);
        bf16x8 bw = *(const bf16x8*)((const char*)&kbT[n0 + r15][0] + q4*16);
        f32x4 ua = {0.f,0.f,0.f,0.f};
        f32x4 wa = {0.f,0.f,0.f,0.f};
        ua = MFMA16(a, bu, ua);
        wa = MFMA16(a, bw, wa);
        #pragma unroll
        for (int rg=0;rg<4;rg++){
          int row = mt*16 + q4*4 + rg;
          int col = n0 + r15;
          u_[(chk*32 + row)*256 + col] = f2bf(ua[rg]);
          w_[(chk*32 + row)*256 + col] = f2bf(wa[rg]);
        }
      }
    }
  }
}

// ---------------- attn128 = tril_incl(q128 @ k128^T), packed lower tiles ----------------
__global__ __launch_bounds__(256,2) void k_attn128(const u16* __restrict__ qn,
                                                   const u16* __restrict__ kn,
                                                   u16* __restrict__ att){
  const int g = blockIdx.x;            // bh*32 + sc
  const int bh = g >> 5, sc = g & 31;
  const int b = bh >> 2, h = bh & 3;
  const int tid = threadIdx.x, lane = tid&63, wv = tid>>6;
  const int r15 = lane&15, q4 = lane>>4;
  const int tok0 = b*4096 + sc*128;
  const f32x4 fz = {0.f,0.f,0.f,0.f};
  u16* base = att + (size_t)g*36*256;
  #pragma unroll
  for (int ti=0; ti<8; ++ti){
    #pragma unroll
    for (int tj=0; tj<=ti; ++tj){
      if (((ti+tj)&3) != wv) continue;
      f32x4 acc = fz;
      const u16* qp = qn + (size_t)(tok0 + ti*16 + r15)*1024 + h*256 + q4*8;
      const u16* kp = kn + (size_t)(tok0 + tj*16 + r15)*1024 + h*256 + q4*8;
      #pragma unroll
      for (int ks=0; ks<8; ++ks)
        acc = MFMA16(*(const bf16x8*)(qp + ks*32), *(const bf16x8*)(kp + ks*32), acc);
      u16* op = base + (size_t)(((ti*(ti+1))>>1) + tj)*256;
      #pragma unroll
      for (int rg=0; rg<4; ++rg){
        float vv = acc[rg];
        if (ti==tj && r15 > q4*4+rg) vv = 0.f;
        op[(q4*4+rg)*16 + r15] = f2bf(vv);
      }
    }
  }
}

// ---------------- pairwise UT composition: u_b -= M u_a, w_b -= M w_a, M = w_b k_a^T ----
template<int HS>
__global__ __launch_bounds__(256,1) void k_compose(const u16* __restrict__ kn,
                                                   u16* __restrict__ u_,
                                                   u16* __restrict__ w_){
  const int g = blockIdx.x;
  const int ppb = 2048/HS;
  const int bh = g / ppb, pr = g % ppb;
  const int b = bh>>2, h = bh&3;
  const int ta = pr*2*HS, tb2 = ta + HS;
  const int tid = threadIdx.x, lane = tid&63, wv = tid>>6;
  const int r15 = lane&15, q4 = lane>>4;
  __shared__ u16 uaT[256][HS+8];
  __shared__ u16 waT[256][HS+8];
  __shared__ u16 Ms[HS][HS+8];
  const f32x4 fz = {0.f,0.f,0.f,0.f};
  // stage transposes of a-rows of u,w
  {
    const int tpr = 256/HS;
    const int jr = tid / tpr;
    const int dg = (tid % tpr) * HS;
    const u16* us = u_ + (size_t)(bh*4096 + ta + jr)*256 + dg;
    const u16* wsc = w_ + (size_t)(bh*4096 + ta + jr)*256 + dg;
    #pragma unroll
    for (int e0=0; e0<HS; e0+=8){
      u16x8 xu = *(const u16x8*)(us + e0);
      u16x8 xw = *(const u16x8*)(wsc + e0);
      #pragma unroll
      for (int e=0;e<8;e++){ uaT[dg+e0+e][jr] = xu[e]; waT[dg+e0+e][jr] = xw[e]; }
    }
  }
  // M = w_b @ k_a^T  (HS x HS)
  constexpr int NT = HS/16;
  for (int t = wv; t < NT*NT; t += 4){
    int ti = t / NT, tj = t % NT;
    f32x4 acc = fz;
    const u16* ap = w_ + (size_t)(bh*4096 + tb2 + ti*16 + r15)*256 + q4*8;
    const u16* bp = kn + (size_t)(b*4096 + ta + tj*16 + r15)*1024 + h*256 + q4*8;
    #pragma unroll
    for (int ks=0; ks<8; ++ks)
      acc = MFMA16(*(const bf16x8*)(ap + ks*32), *(const bf16x8*)(bp + ks*32), acc);
    #pragma unroll
    for (int rg=0; rg<4; ++rg)
      Ms[ti*16 + q4*4 + rg][tj*16 + r15] = f2bf(acc[rg]);
  }
  __syncthreads();
  // updates of b-rows
  for (int t = wv; t < NT*16; t += 4){
    int ti = t >> 4, nj = t & 15;
    f32x4 aU = fz, aW = fz;
    #pragma unroll
    for (int js=0; js<HS/32; ++js){
      bf16x8 a  = *(const bf16x8*)((const char*)&Ms[ti*16 + r15][0] + js*64 + q4*16);
      bf16x8 bu = *(const bf16x8*)((const char*)&uaT[nj*16 + r15][0] + js*64 + q4*16);
      bf16x8 bw = *(const bf16x8*)((const char*)&waT[nj*16 + r15][0] + js*64 + q4*16);
      aU = MFMA16(a, bu, aU);
      aW = MFMA16(a, bw, aW);
    }
    #pragma unroll
    for (int rg=0; rg<4; ++rg){
      size_t off = (size_t)(bh*4096 + tb2 + ti*16 + q4*4 + rg)*256 + nj*16 + r15;
      u_[off] = f2bf(bf2f(u_[off]) - aU[rg]);
      w_[off] = f2bf(bf2f(w_[off]) - aW[rg]);
    }
  }
}

// ---------------- scan over 32 superchunks of 128; grid = 16 bh x 16 dv (XCD-pinned) ---
struct Pref { u16x8 wf[2][8]; u16x4 uv[2]; };

#define SBAR() do{ asm volatile("s_waitcnt lgkmcnt(0)" ::: "memory"); \
                   __builtin_amdgcn_s_barrier(); \
                   asm volatile("" ::: "memory"); }while(0)

#define SPREF128(C, SC) { \
  _Pragma("unroll") for (int rt=0; rt<2; ++rt){ \
    const u16* wp = w_ + (size_t)(ubase + (SC)*128 + (wv*2+rt)*16 + r15)*256 + q4*8; \
    _Pragma("unroll") for (int ks=0; ks<8; ++ks) C.wf[rt][ks] = *(const u16x8*)(wp + ks*32); \
    const u16* up = u_ + (size_t)(ubase + (SC)*128 + (wv*2+rt)*16 + q4*4)*256 + dv0 + r15; \
    u16x4 t_; \
    _Pragma("unroll") for (int rg=0; rg<4; ++rg) t_[rg] = up[rg*256]; \
    C.uv[rt] = t_; } }

#define SBODY128(C, N, SC, CB, NB) { \
  { const int scn = ((SC)+1 < 32) ? (SC)+1 : 31; SPREF128(N, scn); } \
  u16x8 kf[4][4]; \
  _Pragma("unroll") for (int mt=0; mt<4; ++mt) \
    _Pragma("unroll") for (int sl=0; sl<4; ++sl) \
      kf[mt][sl] = *(const u16x8*)(kTb + ((size_t)(chkbase + (SC)*4 + sl)*256 + wv*64 + mt*16 + r15)*32 + q4*8); \
  u16x8 at[2][4]; u16x8 qf[2][8]; \
  _Pragma("unroll") for (int rt=0; rt<2; ++rt){ \
    const int R = wv*2+rt; \
    const u16* ab = att + (size_t)((bh*32 + (SC))*36 + ((R*(R+1))>>1))*256 + r15*16 + (q4&1)*8; \
    _Pragma("unroll") for (int js=0; js<4; ++js){ \
      if (js <= (R>>1)){ \
        int tj = 2*js + (q4>>1); \
        u16x8 z = {0,0,0,0,0,0,0,0}; \
        at[rt][js] = (tj <= R) ? *(const u16x8*)(ab + (size_t)tj*256) : z; } } \
    const u16* qp = qn + (size_t)(qbase + (SC)*128 + R*16 + r15)*1024 + h*256 + q4*8; \
    _Pragma("unroll") for (int ks=0; ks<8; ++ks) qf[rt][ks] = *(const u16x8*)(qp + ks*32); } \
  bf16x8 sf[8]; \
  _Pragma("unroll") for (int ks=0; ks<8; ++ks) \
    sf[ks] = *(const bf16x8*)((const char*)&Sb[CB][r15][0] + ks*64 + q4*16); \
  _Pragma("unroll") for (int rt=0; rt<2; ++rt){ \
    f32x4 ua = fz; \
    _Pragma("unroll") for (int ks=0; ks<8; ++ks) ua = MFMA16(*(const bf16x8*)&C.wf[rt][ks], sf[ks], ua); \
    u16x4 pk; \
    _Pragma("unroll") for (int rg=0; rg<4; ++rg) pk[rg] = f2bf(bf2f(C.uv[rt][rg]) - ua[rg]); \
    *(u16x4*)&uT[r15][(wv*2+rt)*16 + q4*4] = pk; } \
  SBAR(); \
  bf16x8 bu[4]; \
  _Pragma("unroll") for (int sl=0; sl<4; ++sl) \
    bu[sl] = *(const bf16x8*)((const char*)&uT[r15][0] + sl*64 + q4*16); \
  _Pragma("unroll") for (int rt=0; rt<2; ++rt){ \
    const int R = wv*2+rt; \
    f32x4 oa = fz; \
    _Pragma("unroll") for (int ks=0; ks<8; ++ks) oa = MFMA16(*(const bf16x8*)&qf[rt][ks], sf[ks], oa); \
    _Pragma("unroll") for (int js=0; js<4; ++js) \
      if (js <= (R>>1)) oa = MFMA16(*(const bf16x8*)&at[rt][js], bu[js], oa); \
    _Pragma("unroll") for (int rg=0; rg<4; ++rg) \
      od[(size_t)(qbase + (SC)*128 + R*16 + q4*4 + rg)*1024 + h*256 + dv0 + r15] = f2bf(oa[rg]); } \
  _Pragma("unroll") for (int mt=0; mt<4; ++mt){ \
    _Pragma("unroll") for (int sl=0; sl<4; ++sl) \
      Sacc[mt] = MFMA16(*(const bf16x8*)&kf[mt][sl], bu[sl], Sacc[mt]); \
    u16x4 pk; \
    _Pragma("unroll") for (int rg=0; rg<4; ++rg) pk[rg] = f2bf(Sacc[mt][rg]); \
    *(u16x4*)&Sb[NB][r15][wv*64 + mt*16 + q4*4] = pk; } \
  SBAR(); }

__global__ __launch_bounds__(256,1) void k_scan128(
    const u16* __restrict__ qn, const u16* __restrict__ kTb,
    const u16* __restrict__ u_, const u16* __restrict__ w_,
    const u16* __restrict__ att, u16* __restrict__ od)
{
  const int bid = blockIdx.x;
  const int bh  = (bid & 7) | (((bid >> 3) & 1) << 3);
  const int dv0 = (bid >> 4) * 16;
  const int b = bh >> 2, h = bh & 3;
  const int tid = threadIdx.x, lane = tid & 63, wv = tid >> 6;
  const int r15 = lane & 15, q4 = lane >> 4;
  const int chkbase = bh * 128;
  const int ubase = bh * 4096;
  const int qbase = b * 4096;

  __shared__ u16 Sb[2][16][264];
  __shared__ u16 uT[16][136];

  for (int i = tid; i < 2*16*264; i += 256) (&Sb[0][0][0])[i] = 0;
  const f32x4 fz = {0.f,0.f,0.f,0.f};
  f32x4 Sacc[4];
  #pragma unroll
  for (int mt=0; mt<4; ++mt) Sacc[mt] = fz;
  Pref cA, cB;
  SPREF128(cA, 0);
  __syncthreads();

  for (int sc = 0; sc < 32; sc += 2){
    SBODY128(cA, cB, sc,   0, 1)
    SBODY128(cB, cA, sc+1, 1, 0)
  }
}

// ---------------- router features ----------------
__global__ __launch_bounds__(256) void k_feats(
    const float* __restrict__ Xf, const u16* __restrict__ lo, const u16* __restrict__ mo,
    const u16* __restrict__ de, const u16* __restrict__ vv, u16* __restrict__ feat)
{
  const int m = blockIdx.x;
  const int tid = threadIdx.x, lane = tid & 63, hh = tid >> 6;
  {
    float4 xv = *(const float4*)(Xf + m*1024 + tid*4);
    u16x4 o; o[0]=f2bf(xv.x); o[1]=f2bf(xv.y); o[2]=f2bf(xv.z); o[3]=f2bf(xv.w);
    *(u16x4*)(feat + m*1088 + tid*4) = o;
  }
  if (tid < 8) feat[m*1088 + 1080 + tid] = 0;
  const int base = m*1024 + hh*256 + lane*4;
  u16x4 a0 = *(const u16x4*)(lo + base);
  u16x4 a1 = *(const u16x4*)(mo + base);
  u16x4 a2 = *(const u16x4*)(de + base);
  u16x4 a3 = *(const u16x4*)(vv + base);
  float s[14];
  #pragma unroll
  for (int i=0;i<14;i++) s[i]=0.f;
  #pragma unroll
  for (int e=0;e<4;e++){
    float L = bf2f(a0[e]), Mm = bf2f(a1[e]), D = bf2f(a2[e]), V = bf2f(a3[e]);
    s[0]+=L; s[1]+=L*L; s[2]+=Mm; s[3]+=Mm*Mm; s[4]+=D; s[5]+=D*D; s[6]+=V; s[7]+=V*V;
    s[8]+=L*Mm; s[9]+=L*D; s[10]+=L*V; s[11]+=Mm*D; s[12]+=Mm*V; s[13]+=D*V;
  }
  #pragma unroll
  for (int i=0;i<14;i++) s[i] = wred(s[i]);
  if (lane == 0){
    const float inv = 1.f/256.f, invv = 1.f/255.f;
    u16* fb = feat + m*1088 + 1024;
    float mn[4] = {s[0]*inv, s[2]*inv, s[4]*inv, s[6]*inv};
    float vr[4] = {(s[1]-256.f*mn[0]*mn[0])*invv, (s[3]-256.f*mn[1]*mn[1])*invv,
                   (s[5]-256.f*mn[2]*mn[2])*invv, (s[7]-256.f*mn[3]*mn[3])*invv};
    #pragma unroll
    for (int i=0;i<4;i++){ fb[(2*i)*4 + hh] = f2bf(mn[i]); fb[(2*i+1)*4 + hh] = f2bf(vr[i]); }
    #pragma unroll
    for (int i=0;i<6;i++) fb[(8+i)*4 + hh] = f2bf(s[8+i]*inv);
  }
}

// ---------------- mix + MixNorm + out RMSNorm ----------------
__global__ __launch_bounds__(256) void k_mix(
    const u16* __restrict__ lo, const u16* __restrict__ mo, const u16* __restrict__ de,
    const u16* __restrict__ vv, const float* __restrict__ p,
    const float* __restrict__ mixw, const float* __restrict__ onw, u16* __restrict__ on)
{
  const int m = blockIdx.x;
  const int tid = threadIdx.x, lane = tid&63, hh = tid>>6;
  const int dbase = lane*4;
  const int base = m*1024 + hh*256 + dbase;
  float4 pv = *(const float4*)(p + m*16 + hh*4);
  u16x4 a0 = *(const u16x4*)(lo + base);
  u16x4 a1 = *(const u16x4*)(mo + base);
  u16x4 a2 = *(const u16x4*)(de + base);
  u16x4 a3 = *(const u16x4*)(vv + base);
  float g[4]; float ss = 0.f;
  #pragma unroll
  for (int e=0;e<4;e++){
    float x = pv.x*bf2f(a0[e]) + pv.y*bf2f(a1[e]) + pv.z*bf2f(a2[e]) + pv.w*bf2f(a3[e]);
    g[e]=x; ss += x*x;
  }
  ss = wred(ss);
  float r1 = rsqrtf(ss*(1.f/256.f) + 1e-5f);
  float ss2 = 0.f;
  #pragma unroll
  for (int e=0;e<4;e++){ g[e] = g[e]*r1*mixw[hh*256 + dbase + e]; ss2 += g[e]*g[e]; }
  ss2 = wred(ss2);
  float r2 = rsqrtf(ss2*(1.f/256.f) + 1e-5f);
  u16x4 o;
  #pragma unroll
  for (int e=0;e<4;e++) o[e] = f2bf(g[e]*r2*onw[dbase + e]);
  *(u16x4*)(on + base) = o;
}

// ==================================================================================
extern "C" void kernel_launch(void* const* d_in, const int* in_sizes, int n_in,
                              void* d_out, int out_size, void* d_ws, size_t ws_size,
                              hipStream_t stream)
{
  const float* X   = (const float*)d_in[0];
  const float* Wq  = (const float*)d_in[1];
  const float* Wk  = (const float*)d_in[2];
  const float* Wv  = (const float*)d_in[3];
  const float* Wb  = (const float*)d_in[4];
  const float* cqw = (const float*)d_in[5];
  const float* ckw = (const float*)d_in[6];
  const float* cvw = (const float*)d_in[7];
  const float* lw  = (const float*)d_in[8];
  const float* mw  = (const float*)d_in[9];
  const float* rw1 = (const float*)d_in[10];
  const float* rb1 = (const float*)d_in[11];
  const float* rw2 = (const float*)d_in[12];
  const float* rb2 = (const float*)d_in[13];
  const float* mixw= (const float*)d_in[14];
  const float* onw = (const float*)d_in[15];
  const float* Wo  = (const float*)d_in[16];

  char* ws = (char*)d_ws;
  const size_t SLOT = 33554432;   // 16384*1024*2
  char* s0 = ws;
  char* s1 = ws + 1*SLOT;
  char* s2 = ws + 2*SLOT;
  char* s3 = ws + 3*SLOT;
  char* s4 = ws + 4*SLOT;
  char* s5 = ws + 5*SLOT;
  char* s6 = ws + 6*SLOT;        // kTb
  char* ext = ws + 7*SLOT;
  u16*   att128 = (u16*)(ext);                       // 9,437,184  (16*32*36*256*2)
  float* pb    = (float*)(ext + 9437184);            // 1,048,576
  float* betab = (float*)(ext + 9437184 + 1048576);  // 262,144
  char*  wsp   = ext + 9437184 + 1048576 + 262144;
  u16* Wot = (u16*)(wsp);                            // 2,097,152
  u16* w1t = (u16*)(wsp + 2097152);                  // 4,734,976
  u16* w2t = (u16*)(wsp + 2097152 + 4734976);        // 69,632
  float* b1p = (float*)(wsp + 2097152 + 4734976 + 69632);
  // Wq/Wk/Wv transposes alias the att128 region (dead before k_attn128 writes it)
  u16* Wqt = (u16*)(ext);
  u16* Wkt = (u16*)(ext + 2097152);
  u16* Wvt = (u16*)(ext + 4194304);

  // role aliases (lifetime-disjoint)
  u16* Xb    = (u16*)s0;
  u16* rawb  = (u16*)s1;
  u16* qnb   = (u16*)s2;
  u16* knb   = (u16*)s3;
  u16* vpb   = (u16*)s4;
  u16* ub    = (u16*)s0;   // after beta
  u16* wbuf  = (u16*)s1;   // after conv v
  u16* odb   = (u16*)s5;
  u16* kTbp  = (u16*)s6;
  u16* lob   = (u16*)s2;   // after scan
  u16* mob   = (u16*)s3;   // after scan
  u16* featb = (u16*)s0;   // after scan
  u16* onb   = (u16*)s0;   // after router gemm

  // prep
  k_zero<<<1024,256,0,stream>>>(pb, 262144);
  k_cvt<<<16384,256,0,stream>>>(X, Xb, 16777216);
  k_tr<<<dim3(32,32),256,0,stream>>>(Wq, Wqt, 1024,1024,1024,1024);
  k_tr<<<dim3(32,32),256,0,stream>>>(Wk, Wkt, 1024,1024,1024,1024);
  k_tr<<<dim3(32,32),256,0,stream>>>(Wv, Wvt, 1024,1024,1024,1024);
  k_tr<<<dim3(32,32),256,0,stream>>>(Wo, Wot, 1024,1024,1024,1024);
  k_tr<<<dim3(68,34),256,0,stream>>>(rw1, w1t, 1080,2160,1088,2176);
  k_pad_w2t<<<dim3(9,16),256,0,stream>>>(rw2, w2t);
  k_pad_b1<<<9,256,0,stream>>>(rb1, b1p);
  // projections + convs
  k_gemm<<<dim3(8,128),256,0,stream>>>(Xb, Wqt, rawb, 16384,1024,1024, 0);
  k_conv<<<16384,256,0,stream>>>(rawb, cqw, qnb, 1);
  k_gemm<<<dim3(8,128),256,0,stream>>>(Xb, Wkt, rawb, 16384,1024,1024, 0);
  k_conv<<<16384,256,0,stream>>>(rawb, ckw, knb, 1);
  k_gemm<<<dim3(8,128),256,0,stream>>>(Xb, Wvt, rawb, 16384,1024,1024, 0);
  k_conv<<<16384,256,0,stream>>>(rawb, cvw, vpb, 0);
  k_beta<<<4096,256,0,stream>>>(Xb, Wb, betab);   // last use of Xb
  // delta rule: chunk-local, then compose 32->64->128, then 32-step scan
  k_chunk<<<2048,256,0,stream>>>(qnb, knb, vpb, betab, ub, wbuf);
  k_attn128<<<512,256,0,stream>>>(qnb, knb, att128);   // overwrites Wq/Wk/Wv transposes (dead)
  k_trk<<<2048,256,0,stream>>>(knb, kTbp);
  k_compose<32><<<1024,256,0,stream>>>(knb, ub, wbuf);
  k_compose<64><<<512,256,0,stream>>>(knb, ub, wbuf);
  k_scan128<<<256,256,0,stream>>>(qnb, kTbp, ub, wbuf, att128, odb);
  // local/mid convs
  k_localmid<<<dim3(128,4,4),256,0,stream>>>(vpb, lw, mw, lob, mob);
  // router
  k_feats<<<16384,256,0,stream>>>(X, lob, mob, odb, vpb, featb);
  k_gemm_router<<<dim3(17,128),256,0,stream>>>(featb, w1t, b1p, w2t, pb);
  k_softm<<<64,256,0,stream>>>(pb, rb2);
  // mix + output projection
  k_mix<<<16384,256,0,stream>>>(lob, mob, odb, vpb, pb, mixw, onw, onb);
  k_gemm<<<dim3(8,128),256,0,stream>>>(onb, Wot, d_out, 16384,1024,1024, 1);
}